// Round 7
// baseline (328.767 us; speedup 1.0000x reference)
//
#include <hip/hip_runtime.h>
#include <hip/hip_bf16.h>
#include <math.h>

// ---- problem constants (fixed by setup_inputs) ----
#define B_N      8192
#define IN_DIM   784
#define HID      256
#define DL       8
#define NC       48
#define CH       64
#define NCLS     10
#define T_ITERS  5
#define TILES    128        // B_N / 64

#define DT_      0.12f
#define CLAMP_   3.0f
#define GAIN_    0.06f
// b = log2(e)/(2*sigma_i^2) = 0.50093578 ; sigma_e = sigma_i/2 -> E-exp = 4x I-exp.
// u = sqrt(b)*z ; Gram MFMA computes out = <ui,uj> - |ui|^2/2 - |uj|^2/2
// = -0.5*b*dist2 -> e1 = exp2(out); Ki-term = e1^2, Ke-term = e1^8.
#define SQIL2    0.70776814f
#define ONE_BF16 0x3F80u

#if defined(__has_builtin)
#if __has_builtin(__builtin_amdgcn_exp2f)
#define EXP2(x) __builtin_amdgcn_exp2f(x)
#endif
#endif
#ifndef EXP2
#define EXP2(x) exp2f(x)
#endif

typedef __attribute__((ext_vector_type(8))) short short8v;  // 8 bf16 (4 VGPRs)
typedef __attribute__((ext_vector_type(4))) float f32x4;    // MFMA C/D frag

__device__ __forceinline__ unsigned int pack_bf16_rhu(float lo, float hi) {
    unsigned int b0 = __builtin_bit_cast(unsigned int, lo);
    unsigned int b1 = __builtin_bit_cast(unsigned int, hi);
    return ((b0 + 0x8000u) >> 16) | ((b1 + 0x8000u) & 0xFFFF0000u);
}
__device__ __forceinline__ unsigned short bf16_1(float x) {
    return (unsigned short)((__builtin_bit_cast(unsigned int, x) + 0x8000u) >> 16);
}
__device__ __forceinline__ float bf16_to_f(unsigned short h) {
    return __builtin_bit_cast(float, ((unsigned int)h) << 16);
}

// split one z row (scaled) into hi/lo bf16 + c constant pair (bit-identical
// to the round-6 in-line version)
__device__ __forceinline__ void z_split(const float4 a, const float4 b,
                                        uint4& Whi, uint4& Wlo, unsigned int& Wc)
{
    float u[8] = {SQIL2*a.x, SQIL2*a.y, SQIL2*a.z, SQIL2*a.w,
                  SQIL2*b.x, SQIL2*b.y, SQIL2*b.z, SQIL2*b.w};
    float sq = 0.f;
    #pragma unroll
    for (int d = 0; d < 8; ++d) sq = fmaf(u[d], u[d], sq);
    float cn = -0.5f * sq;
    unsigned short hi[8]; float lo[8];
    #pragma unroll
    for (int d = 0; d < 8; ++d) {
        hi[d] = bf16_1(u[d]);
        lo[d] = u[d] - bf16_to_f(hi[d]);
    }
    unsigned short ch_ = bf16_1(cn);
    unsigned short cl_ = bf16_1(cn - bf16_to_f(ch_));
    Whi.x = (unsigned int)hi[0] | ((unsigned int)hi[1] << 16);
    Whi.y = (unsigned int)hi[2] | ((unsigned int)hi[3] << 16);
    Whi.z = (unsigned int)hi[4] | ((unsigned int)hi[5] << 16);
    Whi.w = (unsigned int)hi[6] | ((unsigned int)hi[7] << 16);
    Wlo.x = pack_bf16_rhu(lo[0], lo[1]); Wlo.y = pack_bf16_rhu(lo[2], lo[3]);
    Wlo.z = pack_bf16_rhu(lo[4], lo[5]); Wlo.w = pack_bf16_rhu(lo[6], lo[7]);
    Wc = (unsigned int)ch_ | ((unsigned int)cl_ << 16);
}

// ============ encoder GEMM1: H1 = tanh(x @ W1 + b1) ============
// 32x64 tile, BK=16, 256 threads, 2x4 micro — 1024 blocks (4/CU) for
// latency hiding; per-output k-order identical to previous round.
__global__ __launch_bounds__(256) void k_gemm1_tanh(
    const float* __restrict__ x, const float* __restrict__ W1,
    const float* __restrict__ b1, float* __restrict__ H1)
{
    __shared__ float As[16][36];   // [k][m], 32 rows + pad
    __shared__ float Bs[16][64];   // [k][n]
    const int tid = threadIdx.x;
    const int row0 = blockIdx.x * 32;
    const int col0 = blockIdx.y * 64;
    const int tr = tid >> 4, tc = tid & 15;
    float acc[2][4] = {};
    for (int k0 = 0; k0 < IN_DIM; k0 += 16) {
        if (tid < 128) {
            int m = tid >> 2, kq = tid & 3;
            float4 v = *(const float4*)(x + (size_t)(row0 + m) * IN_DIM + k0 + kq * 4);
            As[kq*4+0][m] = v.x; As[kq*4+1][m] = v.y;
            As[kq*4+2][m] = v.z; As[kq*4+3][m] = v.w;
        }
        {
            int kk = tid >> 4, n4 = tid & 15;
            *(float4*)(&Bs[kk][n4*4]) =
                *(const float4*)(W1 + (size_t)(k0 + kk) * HID + col0 + n4 * 4);
        }
        __syncthreads();
        #pragma unroll
        for (int kk = 0; kk < 16; ++kk) {
            float a0 = As[kk][tr*2];
            float a1 = As[kk][tr*2+1];
            float4 b = *(const float4*)(&Bs[kk][tc*4]);
            acc[0][0] += a0*b.x; acc[0][1] += a0*b.y;
            acc[0][2] += a0*b.z; acc[0][3] += a0*b.w;
            acc[1][0] += a1*b.x; acc[1][1] += a1*b.y;
            acc[1][2] += a1*b.z; acc[1][3] += a1*b.w;
        }
        __syncthreads();
    }
    #pragma unroll
    for (int i = 0; i < 2; ++i) {
        int r = row0 + tr*2 + i;
        #pragma unroll
        for (int j = 0; j < 4; ++j) {
            int c = col0 + tc*4 + j;
            H1[(size_t)r * HID + c] = tanhf(acc[i][j] + b1[c]);
        }
    }
}

// ============ GEMM2: z0 = H1 @ W2 + b2 ============
__global__ __launch_bounds__(256) void k_gemm2(
    const float* __restrict__ H1, const float* __restrict__ W2,
    const float* __restrict__ b2, float* __restrict__ zbuf)
{
    __shared__ float W2s[HID][DL];
    const int tid = threadIdx.x;
    for (int l = tid; l < HID * DL; l += 256) W2s[l >> 3][l & 7] = W2[l];
    __syncthreads();
    const int row = blockIdx.x * 32 + (tid >> 3);
    const int d = tid & 7;
    float acc = b2[d];
    const float* hr = H1 + (size_t)row * HID;
    for (int k = 0; k < HID; k += 4) {
        float4 hv = *(const float4*)(hr + k);
        acc += hv.x * W2s[k][d] + hv.y * W2s[k+1][d]
             + hv.z * W2s[k+2][d] + hv.w * W2s[k+3][d];
    }
    zbuf[(size_t)row * DL + d] = acc;
}

// ============ PM field (4 steps) + fused partial-reduce + proj h-update ======
// z-path arithmetic FROZEN (round-3 lesson: approximations / reorderings in
// the stiff flow get chaos-amplified). Also emits sigma-permuted bf16 h^T.
template<int S, bool HP>
__global__ __launch_bounds__(256) void k_pm_proj(
    const float* __restrict__ centers, const float* __restrict__ mus,
    const float* __restrict__ projW, const float* __restrict__ projb,
    float* __restrict__ zbuf, float* __restrict__ hB,
    unsigned short* __restrict__ hTb,
    const float* __restrict__ pAcc, const float* __restrict__ pDen)
{
    __shared__ float4 cs4[NC][2];
    __shared__ float mu_s[NC];
    __shared__ float pW[DL][CH];
    __shared__ float pb[CH];
    const int tid = threadIdx.x;
    for (int l = tid; l < NC * 2; l += 256) cs4[l >> 1][l & 1] = ((const float4*)centers)[l];
    if (tid < NC) mu_s[tid] = mus[tid];
    for (int l = tid; l < DL * CH; l += 256) pW[l >> 6][l & 63] = projW[l];
    if (tid < CH) pb[tid] = projb[tid];
    __syncthreads();

    const int rloc = tid >> 3;
    const int dl = tid & 7;
    const int row = blockIdx.x * 32 + rloc;

    float4 cza[6], czb[6];
    float mur[6];
    #pragma unroll
    for (int k = 0; k < 6; ++k) {
        cza[k] = cs4[dl + 8*k][0];
        czb[k] = cs4[dl + 8*k][1];
        mur[k] = mu_s[dl + 8*k];
    }

    float z[8];
    {
        const float4* zp = (const float4*)(zbuf + (size_t)row * DL);
        float4 a = zp[0], b = zp[1];
        z[0]=a.x; z[1]=a.y; z[2]=a.z; z[3]=a.w;
        z[4]=b.x; z[5]=b.y; z[6]=b.z; z[7]=b.w;
    }

    #pragma unroll
    for (int step = 0; step < 4; ++step) {
        float np = 0.f;
        float gp[8] = {0,0,0,0,0,0,0,0};
        #pragma unroll
        for (int k = 0; k < 6; ++k) {
            float d0 = z[0]-cza[k].x, d1 = z[1]-cza[k].y;
            float d2 = z[2]-cza[k].z, d3 = z[3]-cza[k].w;
            float d4 = z[4]-czb[k].x, d5 = z[5]-czb[k].y;
            float d6 = z[6]-czb[k].z, d7 = z[7]-czb[k].w;
            float r2 = 1e-4f;
            r2 = fmaf(d0,d0,r2); r2 = fmaf(d1,d1,r2);
            r2 = fmaf(d2,d2,r2); r2 = fmaf(d3,d3,r2);
            r2 = fmaf(d4,d4,r2); r2 = fmaf(d5,d5,r2);
            r2 = fmaf(d6,d6,r2); r2 = fmaf(d7,d7,r2);
            float r = sqrtf(r2);
            float mr = mur[k] / r;
            np += mr;
            float t = mr / r2;
            gp[0] = fmaf(-t, d0, gp[0]); gp[1] = fmaf(-t, d1, gp[1]);
            gp[2] = fmaf(-t, d2, gp[2]); gp[3] = fmaf(-t, d3, gp[3]);
            gp[4] = fmaf(-t, d4, gp[4]); gp[5] = fmaf(-t, d5, gp[5]);
            gp[6] = fmaf(-t, d6, gp[6]); gp[7] = fmaf(-t, d7, gp[7]);
        }
        #pragma unroll
        for (int m = 1; m < 8; m <<= 1) {
            np += __shfl_xor(np, m);
            #pragma unroll
            for (int d = 0; d < 8; ++d) gp[d] += __shfl_xor(gp[d], m);
        }
        float s = DT_ / (1.f + np);
        #pragma unroll
        for (int d = 0; d < 8; ++d) {
            z[d] = fmaf(s, gp[d], z[d]);
            z[d] = fminf(fmaxf(z[d], -CLAMP_), CLAMP_);
        }
    }

    {
        float zout = z[0];
        #pragma unroll
        for (int d = 1; d < 8; ++d) zout = (dl == d) ? z[d] : zout;
        zbuf[(size_t)row * DL + dl] = zout;
    }

    // ---- h_in (fused reduce of split partials), then h_mid ----
    const int c0 = dl * 8;
    float hin[8];
    if (HP) {
        float den = 1e-6f;
        #pragma unroll
        for (int s = 0; s < S; ++s) den += pDen[s * B_N + row];
        float inv = GAIN_ / den;
        #pragma unroll
        for (int q = 0; q < 2; ++q) {
            float4 a = {0.f, 0.f, 0.f, 0.f};
            #pragma unroll
            for (int s = 0; s < S; ++s) {
                float4 p = *(const float4*)(pAcc + (size_t)s * B_N * CH
                                            + (size_t)row * CH + c0 + q * 4);
                a.x += p.x; a.y += p.y; a.z += p.z; a.w += p.w;
            }
            float4 hm = *(const float4*)(hB + (size_t)row * CH + c0 + q * 4);
            hin[q*4+0] = fmaf(inv, a.x, hm.x);
            hin[q*4+1] = fmaf(inv, a.y, hm.y);
            hin[q*4+2] = fmaf(inv, a.z, hm.z);
            hin[q*4+3] = fmaf(inv, a.w, hm.w);
        }
    } else {
        #pragma unroll
        for (int k = 0; k < 8; ++k) hin[k] = 0.f;
    }
    #pragma unroll
    for (int k = 0; k < 8; ++k) {
        int c = c0 + k;
        float s = pb[c];
        #pragma unroll
        for (int dd = 0; dd < DL; ++dd) s = fmaf(z[dd], pW[dd][c], s);
        hin[k] = 0.9f * hin[k] + 0.1f * tanhf(s);
    }
    float4 o0 = {hin[0], hin[1], hin[2], hin[3]};
    float4 o1 = {hin[4], hin[5], hin[6], hin[7]};
    *(float4*)(hB + (size_t)row * CH + c0)     = o0;
    *(float4*)(hB + (size_t)row * CH + c0 + 4) = o1;

    // sigma-permuted transposed bf16 h_mid for lateral staging
    {
        const int jl = row & 63;
        const int colp = (jl & 35) | ((jl & 12) << 1) | ((jl & 16) >> 2);
        const size_t tb = (size_t)(row & ~63) + colp;
        #pragma unroll
        for (int k = 0; k < 8; ++k)
            hTb[(size_t)(c0 + k) * B_N + tb] = bf16_1(hin[k]);
    }
}

// ============ lateral EI: Gram-MFMA weights + MFMA K@h, 32 i/wave ============
// 128 threads = 2 waves per block; each wave owns TWO 16-i sets (A: rows
// rowbase+32wv..+15, B: +16..+31). The 4 zA reads and 8 hsT reads per 64-j
// tile now feed 2048 pairs (halved LDS-pipe per pair vs 16 i/wave).
template<int S>
__global__ __launch_bounds__(128, 2) void k_lateral(
    const float* __restrict__ zbuf, const unsigned short* __restrict__ hTb,
    float* __restrict__ pAcc, float* __restrict__ pDen)
{
    __shared__ __align__(16) unsigned short zA[2][64 * 24]; // 48B rows: hi|lo|aux
    __shared__ __align__(16) unsigned short hsT[2][CH][72]; // h^T bf16 (perm cols)
    const int tid  = threadIdx.x;        // 0..127
    const int lane = tid & 63;
    const int wv   = tid >> 6;           // 0..1
    const int l15  = lane & 15;
    const int g    = lane >> 4;
    const int rowbase = blockIdx.x * 64;
    const int t0 = (TILES * blockIdx.y) / S;
    const int t1 = (TILES * (blockIdx.y + 1)) / S;
    const int chS = tid >> 1, hfS = tid & 1;   // h staging: ch row, 32-j half

    // ---- two per-lane Gram B-frags (own i-rows, sets A and B) ----
    short8v bZa, bZb;
    #pragma unroll
    for (int setb = 0; setb < 2; ++setb) {
        const int irow = rowbase + 32 * wv + 16 * setb + l15;
        const float4* zp = (const float4*)(zbuf + (size_t)irow * DL);
        uint4 Whi, Wlo; unsigned int Wc;
        z_split(zp[0], zp[1], Whi, Wlo, Wc);
        union { unsigned int u[4]; short8v v; } uh, ul, ua;
        uh.u[0]=Whi.x; uh.u[1]=Whi.y; uh.u[2]=Whi.z; uh.u[3]=Whi.w;
        ul.u[0]=Wlo.x; ul.u[1]=Wlo.y; ul.u[2]=Wlo.z; ul.u[3]=Wlo.w;
        ua.u[0] = ONE_BF16 | (ONE_BF16 << 16);
        ua.u[1] = Wc; ua.u[2] = 0; ua.u[3] = 0;
        short8v bz = (g == 2) ? ul.v : ((g == 3) ? ua.v : uh.v);
        if (setb == 0) bZa = bz; else bZb = bz;
    }
    const int offsh = (g == 1) ? 8 : ((g == 3) ? 16 : 0);

    short8v bones;
    {
        union { unsigned int u[4]; short8v v; } uo;
        uo.u[0] = uo.u[1] = uo.u[2] = uo.u[3] = ONE_BF16 | (ONE_BF16 << 16);
        bones = uo.v;
    }

    f32x4 accA0 = {0,0,0,0}, accA1 = {0,0,0,0}, accA2 = {0,0,0,0}, accA3 = {0,0,0,0};
    f32x4 accB0 = {0,0,0,0}, accB1 = {0,0,0,0}, accB2 = {0,0,0,0}, accB3 = {0,0,0,0};
    f32x4 acc4A = {0,0,0,0}, acc4B = {0,0,0,0};
    const f32x4 zc = {0,0,0,0};

    // ---- prologue: stage tile t0 into buffer 0 ----
    {
        const int jb = t0 * 64;
        if (tid < 64) {
            const float4* zp = (const float4*)(zbuf + (size_t)(jb + tid) * DL);
            uint4 Whi, Wlo; unsigned int Wc;
            z_split(zp[0], zp[1], Whi, Wlo, Wc);
            uint4 W2v; W2v.x = Wc; W2v.y = ONE_BF16 | (ONE_BF16 << 16);
            W2v.z = 0; W2v.w = 0;
            unsigned short* dst = &zA[0][tid * 24];
            *(uint4*)(dst)      = Whi;
            *(uint4*)(dst + 8)  = Wlo;
            *(uint4*)(dst + 16) = W2v;
        }
        const unsigned short* hs = hTb + (size_t)chS * B_N + jb + hfS * 32;
        *(uint4*)(&hsT[0][chS][hfS*32])      = *(const uint4*)(hs);
        *(uint4*)(&hsT[0][chS][hfS*32 + 8])  = *(const uint4*)(hs + 8);
        *(uint4*)(&hsT[0][chS][hfS*32 + 16]) = *(const uint4*)(hs + 16);
        *(uint4*)(&hsT[0][chS][hfS*32 + 24]) = *(const uint4*)(hs + 24);
    }

    #pragma unroll 1
    for (int jt = t0; jt < t1; ++jt) {
        const int cur = (jt - t0) & 1;
        const bool more = (jt + 1 < t1);
        uint4 h0n, h1n, h2n, h3n;
        float4 zna, znb;
        if (more) {
            const int jb2 = (jt + 1) * 64;
            const unsigned short* hs = hTb + (size_t)chS * B_N + jb2 + hfS * 32;
            h0n = *(const uint4*)(hs);
            h1n = *(const uint4*)(hs + 8);
            h2n = *(const uint4*)(hs + 16);
            h3n = *(const uint4*)(hs + 24);
            if (tid < 64) {
                const float4* zp = (const float4*)(zbuf + (size_t)(jb2 + tid) * DL);
                zna = zp[0]; znb = zp[1];
            }
        }
        __syncthreads();   // buffer[cur] ready

        // ---- Gram: 8 MFMAs (az shared between the two i-sets) ----
        f32x4 gacA[4], gacB[4];
        #pragma unroll
        for (int t = 0; t < 4; ++t) {
            short8v az = *(const short8v*)(&zA[cur][(t * 16 + l15) * 24 + offsh]);
            gacA[t] = __builtin_amdgcn_mfma_f32_16x16x32_bf16(az, bZa, zc, 0, 0, 0);
            gacB[t] = __builtin_amdgcn_mfma_f32_16x16x32_bf16(az, bZb, zc, 0, 0, 0);
        }

        // ---- w path (lane-local, Gram-native j-order) ----
        short8v afrA[2], afrB[2];
        #pragma unroll
        for (int kb = 0; kb < 2; ++kb) {
            float w8[8];
            #pragma unroll
            for (int m = 0; m < 8; ++m) {
                float out = gacA[2 * kb + (m >> 2)][m & 3];
                float e1 = EXP2(out);
                float e2 = e1 * e1;
                float e4 = e2 * e2;
                float e8 = e4 * e4;
                w8[m] = fmaf(0.8f, e8, -e2);
            }
            union { unsigned int u[4]; short8v v; } uf;
            uf.u[0] = pack_bf16_rhu(w8[0], w8[1]);
            uf.u[1] = pack_bf16_rhu(w8[2], w8[3]);
            uf.u[2] = pack_bf16_rhu(w8[4], w8[5]);
            uf.u[3] = pack_bf16_rhu(w8[6], w8[7]);
            afrA[kb] = uf.v;
        }
        #pragma unroll
        for (int kb = 0; kb < 2; ++kb) {
            float w8[8];
            #pragma unroll
            for (int m = 0; m < 8; ++m) {
                float out = gacB[2 * kb + (m >> 2)][m & 3];
                float e1 = EXP2(out);
                float e2 = e1 * e1;
                float e4 = e2 * e2;
                float e8 = e4 * e4;
                w8[m] = fmaf(0.8f, e8, -e2);
            }
            union { unsigned int u[4]; short8v v; } uf;
            uf.u[0] = pack_bf16_rhu(w8[0], w8[1]);
            uf.u[1] = pack_bf16_rhu(w8[2], w8[3]);
            uf.u[2] = pack_bf16_rhu(w8[4], w8[5]);
            uf.u[3] = pack_bf16_rhu(w8[6], w8[7]);
            afrB[kb] = uf.v;
        }

        // ---- K@h + den (b-frags shared between the two i-sets) ----
        #pragma unroll
        for (int kb = 0; kb < 2; ++kb) {
            const int jo = kb * 32 + g * 8;
            short8v b0 = *(const short8v*)&hsT[cur][ 0 + l15][jo];
            short8v b1 = *(const short8v*)&hsT[cur][16 + l15][jo];
            short8v b2 = *(const short8v*)&hsT[cur][32 + l15][jo];
            short8v b3 = *(const short8v*)&hsT[cur][48 + l15][jo];
            accA0 = __builtin_amdgcn_mfma_f32_16x16x32_bf16(afrA[kb], b0, accA0, 0, 0, 0);
            accA1 = __builtin_amdgcn_mfma_f32_16x16x32_bf16(afrA[kb], b1, accA1, 0, 0, 0);
            accA2 = __builtin_amdgcn_mfma_f32_16x16x32_bf16(afrA[kb], b2, accA2, 0, 0, 0);
            accA3 = __builtin_amdgcn_mfma_f32_16x16x32_bf16(afrA[kb], b3, accA3, 0, 0, 0);
            accB0 = __builtin_amdgcn_mfma_f32_16x16x32_bf16(afrB[kb], b0, accB0, 0, 0, 0);
            accB1 = __builtin_amdgcn_mfma_f32_16x16x32_bf16(afrB[kb], b1, accB1, 0, 0, 0);
            accB2 = __builtin_amdgcn_mfma_f32_16x16x32_bf16(afrB[kb], b2, accB2, 0, 0, 0);
            accB3 = __builtin_amdgcn_mfma_f32_16x16x32_bf16(afrB[kb], b3, accB3, 0, 0, 0);
            acc4A = __builtin_amdgcn_mfma_f32_16x16x32_bf16(afrA[kb], bones, acc4A, 0, 0, 0);
            acc4B = __builtin_amdgcn_mfma_f32_16x16x32_bf16(afrB[kb], bones, acc4B, 0, 0, 0);
        }
        __syncthreads();   // done reading buffer[cur]

        // ---- write staged regs into buffer[cur^1] ----
        if (more) {
            const int nb = cur ^ 1;
            if (tid < 64) {
                uint4 Whi, Wlo; unsigned int Wc;
                z_split(zna, znb, Whi, Wlo, Wc);
                uint4 W2v; W2v.x = Wc; W2v.y = ONE_BF16 | (ONE_BF16 << 16);
                W2v.z = 0; W2v.w = 0;
                unsigned short* dst = &zA[nb][tid * 24];
                *(uint4*)(dst)      = Whi;
                *(uint4*)(dst + 8)  = Wlo;
                *(uint4*)(dst + 16) = W2v;
            }
            *(uint4*)(&hsT[nb][chS][hfS*32])      = h0n;
            *(uint4*)(&hsT[nb][chS][hfS*32 + 8])  = h1n;
            *(uint4*)(&hsT[nb][chS][hfS*32 + 16]) = h2n;
            *(uint4*)(&hsT[nb][chS][hfS*32 + 24]) = h3n;
        }
    }

    // ---- epilogue: partials (block covers 64 i-rows: wv*32 + set*16) ----
    float* pA = pAcc + (size_t)blockIdx.y * (B_N * CH) + (size_t)rowbase * CH;
    #pragma unroll
    for (int r = 0; r < 4; ++r) {
        int giA = 32 * wv + g * 4 + r;
        int giB = giA + 16;
        pA[(size_t)giA * CH +  0 + l15] = accA0[r];
        pA[(size_t)giA * CH + 16 + l15] = accA1[r];
        pA[(size_t)giA * CH + 32 + l15] = accA2[r];
        pA[(size_t)giA * CH + 48 + l15] = accA3[r];
        pA[(size_t)giB * CH +  0 + l15] = accB0[r];
        pA[(size_t)giB * CH + 16 + l15] = accB1[r];
        pA[(size_t)giB * CH + 32 + l15] = accB2[r];
        pA[(size_t)giB * CH + 48 + l15] = accB3[r];
    }
    if (l15 == 0) {
        #pragma unroll
        for (int r = 0; r < 4; ++r) {
            pDen[blockIdx.y * B_N + rowbase + 32 * wv + g * 4 + r]      = acc4A[r];
            pDen[blockIdx.y * B_N + rowbase + 32 * wv + 16 + g * 4 + r] = acc4B[r];
        }
    }
}

// ============ final: h = hmid + GAIN*acc/den ; logits = h @ roW + rob ======
template<int S>
__global__ __launch_bounds__(256) void k_logits_h(
    const float* __restrict__ hmid, const float* __restrict__ pAcc,
    const float* __restrict__ pDen, const float* __restrict__ roW,
    const float* __restrict__ rob, float* __restrict__ out_logits,
    float* __restrict__ out_h)
{
    __shared__ float hsh[64][68];
    __shared__ float ro[CH][NCLS];
    __shared__ float rb[NCLS];
    const int tid = threadIdx.x;
    for (int l = tid; l < CH * NCLS; l += 256) ro[l / NCLS][l % NCLS] = roW[l];
    if (tid < NCLS) rb[tid] = rob[tid];
    const int rowbase = blockIdx.x * 64;
    const int r  = tid >> 2;
    const int c0 = (tid & 3) * 16;
    const int row = rowbase + r;
    float den = 1e-6f;
    #pragma unroll
    for (int s = 0; s < S; ++s) den += pDen[s * B_N + row];
    float inv = GAIN_ / den;
    #pragma unroll
    for (int q = 0; q < 4; ++q) {
        float4 a = {0.f, 0.f, 0.f, 0.f};
        #pragma unroll
        for (int s = 0; s < S; ++s) {
            float4 p = *(const float4*)(pAcc + (size_t)s * B_N * CH
                                        + (size_t)row * CH + c0 + q * 4);
            a.x += p.x; a.y += p.y; a.z += p.z; a.w += p.w;
        }
        float4 hm = *(const float4*)(hmid + (size_t)row * CH + c0 + q * 4);
        float4 hv;
        hv.x = fmaf(inv, a.x, hm.x); hv.y = fmaf(inv, a.y, hm.y);
        hv.z = fmaf(inv, a.z, hm.z); hv.w = fmaf(inv, a.w, hm.w);
        *(float4*)(&hsh[r][c0 + q * 4]) = hv;
        *(float4*)(out_h + (size_t)row * CH + c0 + q * 4) = hv;
    }
    __syncthreads();
    for (int idx = tid; idx < 64 * NCLS; idx += 256) {
        int rr = idx / NCLS, o = idx % NCLS;
        float s = rb[o];
        #pragma unroll
        for (int k = 0; k < CH; ++k) s = fmaf(hsh[rr][k], ro[k][o], s);
        out_logits[(size_t)(rowbase + rr) * NCLS + o] = s;
    }
}

// ---- per-split launch helper ----
template<int S>
static void run_all(const float* x, const float* W1, const float* b1,
                    const float* W2, const float* b2, const float* centers,
                    const float* mus, const float* projW, const float* projb,
                    const float* roW, const float* rob,
                    float* ws, float* out, hipStream_t stream)
{
    float* pAcc = ws;
    float* pDen = ws + (size_t)S * B_N * CH;
    float* zbuf = pDen + (size_t)S * B_N;
    float* hB   = zbuf + B_N * DL;
    unsigned short* hTb = (unsigned short*)(hB + B_N * CH);   // B_N*CH bf16
    float* H1   = ws;   // pre-loop only; fits under pAcc (S >= 4)

    float* out_logits = out;
    float* out_z      = out + 81920;
    float* out_h      = out_z + 65536;

    k_gemm1_tanh<<<dim3(B_N / 32, HID / 64), 256, 0, stream>>>(x, W1, b1, H1);
    k_gemm2<<<B_N / 32, 256, 0, stream>>>(H1, W2, b2, zbuf);

    for (int t = 0; t < T_ITERS; ++t) {
        if (t == 0)
            k_pm_proj<S, false><<<B_N / 32, 256, 0, stream>>>(
                centers, mus, projW, projb, zbuf, hB, hTb, pAcc, pDen);
        else
            k_pm_proj<S, true><<<B_N / 32, 256, 0, stream>>>(
                centers, mus, projW, projb, zbuf, hB, hTb, pAcc, pDen);
        k_lateral<S><<<dim3(TILES, S), 128, 0, stream>>>(zbuf, hTb, pAcc, pDen);
    }

    k_logits_h<S><<<TILES, 256, 0, stream>>>(hB, pAcc, pDen, roW, rob,
                                             out_logits, out_h);
    hipMemcpyAsync(out_z, zbuf, (size_t)B_N * DL * sizeof(float),
                   hipMemcpyDeviceToDevice, stream);
}

extern "C" void kernel_launch(void* const* d_in, const int* in_sizes, int n_in,
                              void* d_out, int out_size, void* d_ws, size_t ws_size,
                              hipStream_t stream)
{
    const float* x       = (const float*)d_in[0];
    const float* W1      = (const float*)d_in[1];
    const float* b1      = (const float*)d_in[2];
    const float* W2      = (const float*)d_in[3];
    const float* b2      = (const float*)d_in[4];
    const float* centers = (const float*)d_in[5];
    const float* mus     = (const float*)d_in[6];
    const float* projW   = (const float*)d_in[7];
    const float* projb   = (const float*)d_in[8];
    const float* roW     = (const float*)d_in[9];
    const float* rob     = (const float*)d_in[10];

    float* ws  = (float*)d_ws;
    float* out = (float*)d_out;

    const size_t needS8 = ((size_t)8*B_N*CH + 8*B_N + B_N*DL + B_N*CH + B_N*CH/2) * 4;
    const size_t needS4 = ((size_t)4*B_N*CH + 4*B_N + B_N*DL + B_N*CH + B_N*CH/2) * 4;

    if (ws_size >= needS8)
        run_all<8>(x, W1, b1, W2, b2, centers, mus, projW, projb, roW, rob, ws, out, stream);
    else if (ws_size >= needS4)
        run_all<4>(x, W1, b1, W2, b2, centers, mus, projW, projb, roW, rob, ws, out, stream);
    else
        run_all<2>(x, W1, b1, W2, b2, centers, mus, projW, projb, roW, rob, ws, out, stream);
}

// Round 8
// 307.013 us; speedup vs baseline: 1.0709x; 1.0709x over previous
//
#include <hip/hip_runtime.h>
#include <hip/hip_bf16.h>
#include <math.h>

// ---- problem constants (fixed by setup_inputs) ----
#define B_N      8192
#define IN_DIM   784
#define HID      256
#define DL       8
#define NC       48
#define CH       64
#define NCLS     10
#define T_ITERS  5
#define TILES    128        // B_N / 64

#define DT_      0.12f
#define CLAMP_   3.0f
#define GAIN_    0.06f
// b = log2(e)/(2*sigma_i^2) = 0.50093578 ; sigma_e = sigma_i/2 -> E-exp = 4x I-exp.
// u = sqrt(b)*z ; Gram MFMA computes out = <ui,uj> - |ui|^2/2 - |uj|^2/2
// = -0.5*b*dist2 -> e1 = exp2(out); Ki-term = e1^2, Ke-term = e1^8.
#define SQIL2    0.70776814f
#define ONE_BF16 0x3F80u

#if defined(__has_builtin)
#if __has_builtin(__builtin_amdgcn_exp2f)
#define EXP2(x) __builtin_amdgcn_exp2f(x)
#endif
#endif
#ifndef EXP2
#define EXP2(x) exp2f(x)
#endif

typedef __attribute__((ext_vector_type(8))) short short8v;  // 8 bf16 (4 VGPRs)
typedef __attribute__((ext_vector_type(4))) float f32x4;    // MFMA C/D frag

__device__ __forceinline__ unsigned int pack_bf16_rhu(float lo, float hi) {
    unsigned int b0 = __builtin_bit_cast(unsigned int, lo);
    unsigned int b1 = __builtin_bit_cast(unsigned int, hi);
    return ((b0 + 0x8000u) >> 16) | ((b1 + 0x8000u) & 0xFFFF0000u);
}
__device__ __forceinline__ unsigned short bf16_1(float x) {
    return (unsigned short)((__builtin_bit_cast(unsigned int, x) + 0x8000u) >> 16);
}
__device__ __forceinline__ float bf16_to_f(unsigned short h) {
    return __builtin_bit_cast(float, ((unsigned int)h) << 16);
}

// split one z row (scaled) into hi/lo bf16 + c constant pair
__device__ __forceinline__ void z_split(const float4 a, const float4 b,
                                        uint4& Whi, uint4& Wlo, unsigned int& Wc)
{
    float u[8] = {SQIL2*a.x, SQIL2*a.y, SQIL2*a.z, SQIL2*a.w,
                  SQIL2*b.x, SQIL2*b.y, SQIL2*b.z, SQIL2*b.w};
    float sq = 0.f;
    #pragma unroll
    for (int d = 0; d < 8; ++d) sq = fmaf(u[d], u[d], sq);
    float cn = -0.5f * sq;
    unsigned short hi[8]; float lo[8];
    #pragma unroll
    for (int d = 0; d < 8; ++d) {
        hi[d] = bf16_1(u[d]);
        lo[d] = u[d] - bf16_to_f(hi[d]);
    }
    unsigned short ch_ = bf16_1(cn);
    unsigned short cl_ = bf16_1(cn - bf16_to_f(ch_));
    Whi.x = (unsigned int)hi[0] | ((unsigned int)hi[1] << 16);
    Whi.y = (unsigned int)hi[2] | ((unsigned int)hi[3] << 16);
    Whi.z = (unsigned int)hi[4] | ((unsigned int)hi[5] << 16);
    Whi.w = (unsigned int)hi[6] | ((unsigned int)hi[7] << 16);
    Wlo.x = pack_bf16_rhu(lo[0], lo[1]); Wlo.y = pack_bf16_rhu(lo[2], lo[3]);
    Wlo.z = pack_bf16_rhu(lo[4], lo[5]); Wlo.w = pack_bf16_rhu(lo[6], lo[7]);
    Wc = (unsigned int)ch_ | ((unsigned int)cl_ << 16);
}

// ============ encoder GEMM1: H1 = tanh(x @ W1 + b1) ============
// Round-6 64x64/4x4 body (FP order frozen: z0 reassociation noise is
// chaos-amplified ~1e4x by the PM flow) + 1-barrier double-buffered LDS.
__global__ __launch_bounds__(256) void k_gemm1_tanh(
    const float* __restrict__ x, const float* __restrict__ W1,
    const float* __restrict__ b1, float* __restrict__ H1)
{
    __shared__ float As[2][16][68];   // [buf][k][m], padded
    __shared__ float Bs[2][16][64];   // [buf][k][n]
    const int tid = threadIdx.x;
    const int row0 = blockIdx.x * 64;
    const int col0 = blockIdx.y * 64;
    const int tr = tid >> 4, tc = tid & 15;
    const int am = tid >> 2, akq = tid & 3;       // A staging role
    const int bkk = tid >> 4, bn4 = tid & 15;     // B staging role
    float acc[4][4] = {};

    // prologue: stage k-tile 0 into buffer 0
    {
        float4 va = *(const float4*)(x + (size_t)(row0 + am) * IN_DIM + akq * 4);
        float4 vb = *(const float4*)(W1 + (size_t)bkk * HID + col0 + bn4 * 4);
        As[0][akq*4+0][am] = va.x; As[0][akq*4+1][am] = va.y;
        As[0][akq*4+2][am] = va.z; As[0][akq*4+3][am] = va.w;
        *(float4*)(&Bs[0][bkk][bn4*4]) = vb;
    }

    const int NK = IN_DIM / 16;   // 49
    #pragma unroll 1
    for (int ks = 0; ks < NK; ++ks) {
        const int cur = ks & 1;
        const bool more = (ks + 1 < NK);
        float4 va, vb;
        if (more) {
            const int k0 = (ks + 1) * 16;
            va = *(const float4*)(x + (size_t)(row0 + am) * IN_DIM + k0 + akq * 4);
            vb = *(const float4*)(W1 + (size_t)(k0 + bkk) * HID + col0 + bn4 * 4);
        }
        __syncthreads();   // buffer[cur] fully written
        #pragma unroll
        for (int kk = 0; kk < 16; ++kk) {
            float4 a = *(const float4*)(&As[cur][kk][tr*4]);
            float4 b = *(const float4*)(&Bs[cur][kk][tc*4]);
            float av[4] = {a.x, a.y, a.z, a.w};
            float bv[4] = {b.x, b.y, b.z, b.w};
            #pragma unroll
            for (int i = 0; i < 4; ++i)
                #pragma unroll
                for (int j = 0; j < 4; ++j)
                    acc[i][j] += av[i] * bv[j];
        }
        if (more) {   // write next tile into the other buffer (no 2nd barrier:
            const int nb = cur ^ 1;   // nobody reads buf[nb] until next barrier)
            As[nb][akq*4+0][am] = va.x; As[nb][akq*4+1][am] = va.y;
            As[nb][akq*4+2][am] = va.z; As[nb][akq*4+3][am] = va.w;
            *(float4*)(&Bs[nb][bkk][bn4*4]) = vb;
        }
    }

    const float4 b1c = *(const float4*)(b1 + col0 + tc * 4);
    const float bb[4] = {b1c.x, b1c.y, b1c.z, b1c.w};
    #pragma unroll
    for (int i = 0; i < 4; ++i) {
        int r = row0 + tr*4 + i;
        float4 hv;
        hv.x = tanhf(acc[i][0] + bb[0]);
        hv.y = tanhf(acc[i][1] + bb[1]);
        hv.z = tanhf(acc[i][2] + bb[2]);
        hv.w = tanhf(acc[i][3] + bb[3]);
        *(float4*)(H1 + (size_t)r * HID + col0 + tc * 4) = hv;
    }
}

// ============ GEMM2: z0 = H1 @ W2 + b2 ============
__global__ __launch_bounds__(256) void k_gemm2(
    const float* __restrict__ H1, const float* __restrict__ W2,
    const float* __restrict__ b2, float* __restrict__ zbuf)
{
    __shared__ float W2s[HID][DL];
    const int tid = threadIdx.x;
    for (int l = tid; l < HID * DL; l += 256) W2s[l >> 3][l & 7] = W2[l];
    __syncthreads();
    const int row = blockIdx.x * 32 + (tid >> 3);
    const int d = tid & 7;
    float acc = b2[d];
    const float* hr = H1 + (size_t)row * HID;
    for (int k = 0; k < HID; k += 4) {
        float4 hv = *(const float4*)(hr + k);
        acc += hv.x * W2s[k][d] + hv.y * W2s[k+1][d]
             + hv.z * W2s[k+2][d] + hv.w * W2s[k+3][d];
    }
    zbuf[(size_t)row * DL + d] = acc;
}

// ============ PM field (4 steps) + fused partial-reduce + proj h-update ======
// z-path arithmetic FROZEN (chaos amplification ~1e4x).
template<int S, bool HP>
__global__ __launch_bounds__(256) void k_pm_proj(
    const float* __restrict__ centers, const float* __restrict__ mus,
    const float* __restrict__ projW, const float* __restrict__ projb,
    float* __restrict__ zbuf, float* __restrict__ hB,
    unsigned short* __restrict__ hTb,
    const float* __restrict__ pAcc, const float* __restrict__ pDen)
{
    __shared__ float4 cs4[NC][2];
    __shared__ float mu_s[NC];
    __shared__ float pW[DL][CH];
    __shared__ float pb[CH];
    const int tid = threadIdx.x;
    for (int l = tid; l < NC * 2; l += 256) cs4[l >> 1][l & 1] = ((const float4*)centers)[l];
    if (tid < NC) mu_s[tid] = mus[tid];
    for (int l = tid; l < DL * CH; l += 256) pW[l >> 6][l & 63] = projW[l];
    if (tid < CH) pb[tid] = projb[tid];
    __syncthreads();

    const int rloc = tid >> 3;
    const int dl = tid & 7;
    const int row = blockIdx.x * 32 + rloc;

    float4 cza[6], czb[6];
    float mur[6];
    #pragma unroll
    for (int k = 0; k < 6; ++k) {
        cza[k] = cs4[dl + 8*k][0];
        czb[k] = cs4[dl + 8*k][1];
        mur[k] = mu_s[dl + 8*k];
    }

    float z[8];
    {
        const float4* zp = (const float4*)(zbuf + (size_t)row * DL);
        float4 a = zp[0], b = zp[1];
        z[0]=a.x; z[1]=a.y; z[2]=a.z; z[3]=a.w;
        z[4]=b.x; z[5]=b.y; z[6]=b.z; z[7]=b.w;
    }

    #pragma unroll
    for (int step = 0; step < 4; ++step) {
        float np = 0.f;
        float gp[8] = {0,0,0,0,0,0,0,0};
        #pragma unroll
        for (int k = 0; k < 6; ++k) {
            float d0 = z[0]-cza[k].x, d1 = z[1]-cza[k].y;
            float d2 = z[2]-cza[k].z, d3 = z[3]-cza[k].w;
            float d4 = z[4]-czb[k].x, d5 = z[5]-czb[k].y;
            float d6 = z[6]-czb[k].z, d7 = z[7]-czb[k].w;
            float r2 = 1e-4f;
            r2 = fmaf(d0,d0,r2); r2 = fmaf(d1,d1,r2);
            r2 = fmaf(d2,d2,r2); r2 = fmaf(d3,d3,r2);
            r2 = fmaf(d4,d4,r2); r2 = fmaf(d5,d5,r2);
            r2 = fmaf(d6,d6,r2); r2 = fmaf(d7,d7,r2);
            float r = sqrtf(r2);
            float mr = mur[k] / r;
            np += mr;
            float t = mr / r2;
            gp[0] = fmaf(-t, d0, gp[0]); gp[1] = fmaf(-t, d1, gp[1]);
            gp[2] = fmaf(-t, d2, gp[2]); gp[3] = fmaf(-t, d3, gp[3]);
            gp[4] = fmaf(-t, d4, gp[4]); gp[5] = fmaf(-t, d5, gp[5]);
            gp[6] = fmaf(-t, d6, gp[6]); gp[7] = fmaf(-t, d7, gp[7]);
        }
        #pragma unroll
        for (int m = 1; m < 8; m <<= 1) {
            np += __shfl_xor(np, m);
            #pragma unroll
            for (int d = 0; d < 8; ++d) gp[d] += __shfl_xor(gp[d], m);
        }
        float s = DT_ / (1.f + np);
        #pragma unroll
        for (int d = 0; d < 8; ++d) {
            z[d] = fmaf(s, gp[d], z[d]);
            z[d] = fminf(fmaxf(z[d], -CLAMP_), CLAMP_);
        }
    }

    {
        float zout = z[0];
        #pragma unroll
        for (int d = 1; d < 8; ++d) zout = (dl == d) ? z[d] : zout;
        zbuf[(size_t)row * DL + dl] = zout;
    }

    // ---- h_in (fused reduce of split partials), then h_mid ----
    const int c0 = dl * 8;
    float hin[8];
    if (HP) {
        float den = 1e-6f;
        #pragma unroll
        for (int s = 0; s < S; ++s) den += pDen[s * B_N + row];
        float inv = GAIN_ / den;
        #pragma unroll
        for (int q = 0; q < 2; ++q) {
            float4 a = {0.f, 0.f, 0.f, 0.f};
            #pragma unroll
            for (int s = 0; s < S; ++s) {
                float4 p = *(const float4*)(pAcc + (size_t)s * B_N * CH
                                            + (size_t)row * CH + c0 + q * 4);
                a.x += p.x; a.y += p.y; a.z += p.z; a.w += p.w;
            }
            float4 hm = *(const float4*)(hB + (size_t)row * CH + c0 + q * 4);
            hin[q*4+0] = fmaf(inv, a.x, hm.x);
            hin[q*4+1] = fmaf(inv, a.y, hm.y);
            hin[q*4+2] = fmaf(inv, a.z, hm.z);
            hin[q*4+3] = fmaf(inv, a.w, hm.w);
        }
    } else {
        #pragma unroll
        for (int k = 0; k < 8; ++k) hin[k] = 0.f;
    }
    #pragma unroll
    for (int k = 0; k < 8; ++k) {
        int c = c0 + k;
        float s = pb[c];
        #pragma unroll
        for (int dd = 0; dd < DL; ++dd) s = fmaf(z[dd], pW[dd][c], s);
        hin[k] = 0.9f * hin[k] + 0.1f * tanhf(s);
    }
    float4 o0 = {hin[0], hin[1], hin[2], hin[3]};
    float4 o1 = {hin[4], hin[5], hin[6], hin[7]};
    *(float4*)(hB + (size_t)row * CH + c0)     = o0;
    *(float4*)(hB + (size_t)row * CH + c0 + 4) = o1;

    // sigma-permuted transposed bf16 h_mid for lateral staging
    {
        const int jl = row & 63;
        const int colp = (jl & 35) | ((jl & 12) << 1) | ((jl & 16) >> 2);
        const size_t tb = (size_t)(row & ~63) + colp;
        #pragma unroll
        for (int k = 0; k < 8; ++k)
            hTb[(size_t)(c0 + k) * B_N + tb] = bf16_1(hin[k]);
    }
}

// ============ lateral EI: Gram-MFMA weights + MFMA K@h, 32 i/wave ============
// 128 threads = 2 waves; each wave owns TWO 16-i sets. Single barrier per
// j-tile (double-buffer: writes to buf[nb] can't race reads of buf[cur]).
template<int S>
__global__ __launch_bounds__(128, 2) void k_lateral(
    const float* __restrict__ zbuf, const unsigned short* __restrict__ hTb,
    float* __restrict__ pAcc, float* __restrict__ pDen)
{
    __shared__ __align__(16) unsigned short zA[2][64 * 24]; // 48B rows: hi|lo|aux
    __shared__ __align__(16) unsigned short hsT[2][CH][72]; // h^T bf16 (perm cols)
    const int tid  = threadIdx.x;        // 0..127
    const int lane = tid & 63;
    const int wv   = tid >> 6;           // 0..1
    const int l15  = lane & 15;
    const int g    = lane >> 4;
    const int rowbase = blockIdx.x * 64;
    const int t0 = (TILES * blockIdx.y) / S;
    const int t1 = (TILES * (blockIdx.y + 1)) / S;
    const int chS = tid >> 1, hfS = tid & 1;   // h staging: ch row, 32-j half

    // ---- two per-lane Gram B-frags (own i-rows, sets A and B) ----
    short8v bZa, bZb;
    #pragma unroll
    for (int setb = 0; setb < 2; ++setb) {
        const int irow = rowbase + 32 * wv + 16 * setb + l15;
        const float4* zp = (const float4*)(zbuf + (size_t)irow * DL);
        uint4 Whi, Wlo; unsigned int Wc;
        z_split(zp[0], zp[1], Whi, Wlo, Wc);
        union { unsigned int u[4]; short8v v; } uh, ul, ua;
        uh.u[0]=Whi.x; uh.u[1]=Whi.y; uh.u[2]=Whi.z; uh.u[3]=Whi.w;
        ul.u[0]=Wlo.x; ul.u[1]=Wlo.y; ul.u[2]=Wlo.z; ul.u[3]=Wlo.w;
        ua.u[0] = ONE_BF16 | (ONE_BF16 << 16);
        ua.u[1] = Wc; ua.u[2] = 0; ua.u[3] = 0;
        short8v bz = (g == 2) ? ul.v : ((g == 3) ? ua.v : uh.v);
        if (setb == 0) bZa = bz; else bZb = bz;
    }
    const int offsh = (g == 1) ? 8 : ((g == 3) ? 16 : 0);

    short8v bones;
    {
        union { unsigned int u[4]; short8v v; } uo;
        uo.u[0] = uo.u[1] = uo.u[2] = uo.u[3] = ONE_BF16 | (ONE_BF16 << 16);
        bones = uo.v;
    }

    f32x4 accA0 = {0,0,0,0}, accA1 = {0,0,0,0}, accA2 = {0,0,0,0}, accA3 = {0,0,0,0};
    f32x4 accB0 = {0,0,0,0}, accB1 = {0,0,0,0}, accB2 = {0,0,0,0}, accB3 = {0,0,0,0};
    f32x4 acc4A = {0,0,0,0}, acc4B = {0,0,0,0};
    const f32x4 zc = {0,0,0,0};

    // ---- prologue: stage tile t0 into buffer 0 ----
    {
        const int jb = t0 * 64;
        if (tid < 64) {
            const float4* zp = (const float4*)(zbuf + (size_t)(jb + tid) * DL);
            uint4 Whi, Wlo; unsigned int Wc;
            z_split(zp[0], zp[1], Whi, Wlo, Wc);
            uint4 W2v; W2v.x = Wc; W2v.y = ONE_BF16 | (ONE_BF16 << 16);
            W2v.z = 0; W2v.w = 0;
            unsigned short* dst = &zA[0][tid * 24];
            *(uint4*)(dst)      = Whi;
            *(uint4*)(dst + 8)  = Wlo;
            *(uint4*)(dst + 16) = W2v;
        }
        const unsigned short* hs = hTb + (size_t)chS * B_N + jb + hfS * 32;
        *(uint4*)(&hsT[0][chS][hfS*32])      = *(const uint4*)(hs);
        *(uint4*)(&hsT[0][chS][hfS*32 + 8])  = *(const uint4*)(hs + 8);
        *(uint4*)(&hsT[0][chS][hfS*32 + 16]) = *(const uint4*)(hs + 16);
        *(uint4*)(&hsT[0][chS][hfS*32 + 24]) = *(const uint4*)(hs + 24);
    }

    #pragma unroll 1
    for (int jt = t0; jt < t1; ++jt) {
        const int cur = (jt - t0) & 1;
        const bool more = (jt + 1 < t1);
        uint4 h0n, h1n, h2n, h3n;
        float4 zna, znb;
        if (more) {
            const int jb2 = (jt + 1) * 64;
            const unsigned short* hs = hTb + (size_t)chS * B_N + jb2 + hfS * 32;
            h0n = *(const uint4*)(hs);
            h1n = *(const uint4*)(hs + 8);
            h2n = *(const uint4*)(hs + 16);
            h3n = *(const uint4*)(hs + 24);
            if (tid < 64) {
                const float4* zp = (const float4*)(zbuf + (size_t)(jb2 + tid) * DL);
                zna = zp[0]; znb = zp[1];
            }
        }
        __syncthreads();   // buffer[cur] ready (single barrier per tile)

        // ---- Gram: 8 MFMAs (az shared between the two i-sets) ----
        f32x4 gacA[4], gacB[4];
        __builtin_amdgcn_s_setprio(1);
        #pragma unroll
        for (int t = 0; t < 4; ++t) {
            short8v az = *(const short8v*)(&zA[cur][(t * 16 + l15) * 24 + offsh]);
            gacA[t] = __builtin_amdgcn_mfma_f32_16x16x32_bf16(az, bZa, zc, 0, 0, 0);
            gacB[t] = __builtin_amdgcn_mfma_f32_16x16x32_bf16(az, bZb, zc, 0, 0, 0);
        }
        __builtin_amdgcn_s_setprio(0);

        // ---- w path (lane-local, Gram-native j-order) ----
        short8v afrA[2], afrB[2];
        #pragma unroll
        for (int kb = 0; kb < 2; ++kb) {
            float w8[8];
            #pragma unroll
            for (int m = 0; m < 8; ++m) {
                float out = gacA[2 * kb + (m >> 2)][m & 3];
                float e1 = EXP2(out);
                float e2 = e1 * e1;
                float e4 = e2 * e2;
                float e8 = e4 * e4;
                w8[m] = fmaf(0.8f, e8, -e2);
            }
            union { unsigned int u[4]; short8v v; } uf;
            uf.u[0] = pack_bf16_rhu(w8[0], w8[1]);
            uf.u[1] = pack_bf16_rhu(w8[2], w8[3]);
            uf.u[2] = pack_bf16_rhu(w8[4], w8[5]);
            uf.u[3] = pack_bf16_rhu(w8[6], w8[7]);
            afrA[kb] = uf.v;
        }
        #pragma unroll
        for (int kb = 0; kb < 2; ++kb) {
            float w8[8];
            #pragma unroll
            for (int m = 0; m < 8; ++m) {
                float out = gacB[2 * kb + (m >> 2)][m & 3];
                float e1 = EXP2(out);
                float e2 = e1 * e1;
                float e4 = e2 * e2;
                float e8 = e4 * e4;
                w8[m] = fmaf(0.8f, e8, -e2);
            }
            union { unsigned int u[4]; short8v v; } uf;
            uf.u[0] = pack_bf16_rhu(w8[0], w8[1]);
            uf.u[1] = pack_bf16_rhu(w8[2], w8[3]);
            uf.u[2] = pack_bf16_rhu(w8[4], w8[5]);
            uf.u[3] = pack_bf16_rhu(w8[6], w8[7]);
            afrB[kb] = uf.v;
        }

        // ---- K@h + den (b-frags shared between the two i-sets) ----
        __builtin_amdgcn_s_setprio(1);
        #pragma unroll
        for (int kb = 0; kb < 2; ++kb) {
            const int jo = kb * 32 + g * 8;
            short8v b0 = *(const short8v*)&hsT[cur][ 0 + l15][jo];
            short8v b1 = *(const short8v*)&hsT[cur][16 + l15][jo];
            short8v b2 = *(const short8v*)&hsT[cur][32 + l15][jo];
            short8v b3 = *(const short8v*)&hsT[cur][48 + l15][jo];
            accA0 = __builtin_amdgcn_mfma_f32_16x16x32_bf16(afrA[kb], b0, accA0, 0, 0, 0);
            accA1 = __builtin_amdgcn_mfma_f32_16x16x32_bf16(afrA[kb], b1, accA1, 0, 0, 0);
            accA2 = __builtin_amdgcn_mfma_f32_16x16x32_bf16(afrA[kb], b2, accA2, 0, 0, 0);
            accA3 = __builtin_amdgcn_mfma_f32_16x16x32_bf16(afrA[kb], b3, accA3, 0, 0, 0);
            accB0 = __builtin_amdgcn_mfma_f32_16x16x32_bf16(afrB[kb], b0, accB0, 0, 0, 0);
            accB1 = __builtin_amdgcn_mfma_f32_16x16x32_bf16(afrB[kb], b1, accB1, 0, 0, 0);
            accB2 = __builtin_amdgcn_mfma_f32_16x16x32_bf16(afrB[kb], b2, accB2, 0, 0, 0);
            accB3 = __builtin_amdgcn_mfma_f32_16x16x32_bf16(afrB[kb], b3, accB3, 0, 0, 0);
            acc4A = __builtin_amdgcn_mfma_f32_16x16x32_bf16(afrA[kb], bones, acc4A, 0, 0, 0);
            acc4B = __builtin_amdgcn_mfma_f32_16x16x32_bf16(afrB[kb], bones, acc4B, 0, 0, 0);
        }
        __builtin_amdgcn_s_setprio(0);

        // ---- write staged regs into buffer[cur^1] (no 2nd barrier needed) ----
        if (more) {
            const int nb = cur ^ 1;
            if (tid < 64) {
                uint4 Whi, Wlo; unsigned int Wc;
                z_split(zna, znb, Whi, Wlo, Wc);
                uint4 W2v; W2v.x = Wc; W2v.y = ONE_BF16 | (ONE_BF16 << 16);
                W2v.z = 0; W2v.w = 0;
                unsigned short* dst = &zA[nb][tid * 24];
                *(uint4*)(dst)      = Whi;
                *(uint4*)(dst + 8)  = Wlo;
                *(uint4*)(dst + 16) = W2v;
            }
            *(uint4*)(&hsT[nb][chS][hfS*32])      = h0n;
            *(uint4*)(&hsT[nb][chS][hfS*32 + 8])  = h1n;
            *(uint4*)(&hsT[nb][chS][hfS*32 + 16]) = h2n;
            *(uint4*)(&hsT[nb][chS][hfS*32 + 24]) = h3n;
        }
    }

    // ---- epilogue: partials (block covers 64 i-rows: wv*32 + set*16) ----
    float* pA = pAcc + (size_t)blockIdx.y * (B_N * CH) + (size_t)rowbase * CH;
    #pragma unroll
    for (int r = 0; r < 4; ++r) {
        int giA = 32 * wv + g * 4 + r;
        int giB = giA + 16;
        pA[(size_t)giA * CH +  0 + l15] = accA0[r];
        pA[(size_t)giA * CH + 16 + l15] = accA1[r];
        pA[(size_t)giA * CH + 32 + l15] = accA2[r];
        pA[(size_t)giA * CH + 48 + l15] = accA3[r];
        pA[(size_t)giB * CH +  0 + l15] = accB0[r];
        pA[(size_t)giB * CH + 16 + l15] = accB1[r];
        pA[(size_t)giB * CH + 32 + l15] = accB2[r];
        pA[(size_t)giB * CH + 48 + l15] = accB3[r];
    }
    if (l15 == 0) {
        #pragma unroll
        for (int r = 0; r < 4; ++r) {
            pDen[blockIdx.y * B_N + rowbase + 32 * wv + g * 4 + r]      = acc4A[r];
            pDen[blockIdx.y * B_N + rowbase + 32 * wv + 16 + g * 4 + r] = acc4B[r];
        }
    }
}

// ============ final: h = hmid + GAIN*acc/den ; logits = h @ roW + rob ======
template<int S>
__global__ __launch_bounds__(256) void k_logits_h(
    const float* __restrict__ hmid, const float* __restrict__ pAcc,
    const float* __restrict__ pDen, const float* __restrict__ roW,
    const float* __restrict__ rob, float* __restrict__ out_logits,
    float* __restrict__ out_h)
{
    __shared__ float hsh[64][68];
    __shared__ float ro[CH][NCLS];
    __shared__ float rb[NCLS];
    const int tid = threadIdx.x;
    for (int l = tid; l < CH * NCLS; l += 256) ro[l / NCLS][l % NCLS] = roW[l];
    if (tid < NCLS) rb[tid] = rob[tid];
    const int rowbase = blockIdx.x * 64;
    const int r  = tid >> 2;
    const int c0 = (tid & 3) * 16;
    const int row = rowbase + r;
    float den = 1e-6f;
    #pragma unroll
    for (int s = 0; s < S; ++s) den += pDen[s * B_N + row];
    float inv = GAIN_ / den;
    #pragma unroll
    for (int q = 0; q < 4; ++q) {
        float4 a = {0.f, 0.f, 0.f, 0.f};
        #pragma unroll
        for (int s = 0; s < S; ++s) {
            float4 p = *(const float4*)(pAcc + (size_t)s * B_N * CH
                                        + (size_t)row * CH + c0 + q * 4);
            a.x += p.x; a.y += p.y; a.z += p.z; a.w += p.w;
        }
        float4 hm = *(const float4*)(hmid + (size_t)row * CH + c0 + q * 4);
        float4 hv;
        hv.x = fmaf(inv, a.x, hm.x); hv.y = fmaf(inv, a.y, hm.y);
        hv.z = fmaf(inv, a.z, hm.z); hv.w = fmaf(inv, a.w, hm.w);
        *(float4*)(&hsh[r][c0 + q * 4]) = hv;
        *(float4*)(out_h + (size_t)row * CH + c0 + q * 4) = hv;
    }
    __syncthreads();
    for (int idx = tid; idx < 64 * NCLS; idx += 256) {
        int rr = idx / NCLS, o = idx % NCLS;
        float s = rb[o];
        #pragma unroll
        for (int k = 0; k < CH; ++k) s = fmaf(hsh[rr][k], ro[k][o], s);
        out_logits[(size_t)(rowbase + rr) * NCLS + o] = s;
    }
}

// ---- per-split launch helper ----
template<int S>
static void run_all(const float* x, const float* W1, const float* b1,
                    const float* W2, const float* b2, const float* centers,
                    const float* mus, const float* projW, const float* projb,
                    const float* roW, const float* rob,
                    float* ws, float* out, hipStream_t stream)
{
    float* pAcc = ws;
    float* pDen = ws + (size_t)S * B_N * CH;
    float* zbuf = pDen + (size_t)S * B_N;
    float* hB   = zbuf + B_N * DL;
    unsigned short* hTb = (unsigned short*)(hB + B_N * CH);   // B_N*CH bf16
    float* H1   = ws;   // pre-loop only; fits under pAcc (S >= 4)

    float* out_logits = out;
    float* out_z      = out + 81920;
    float* out_h      = out_z + 65536;

    k_gemm1_tanh<<<dim3(B_N / 64, HID / 64), 256, 0, stream>>>(x, W1, b1, H1);
    k_gemm2<<<B_N / 32, 256, 0, stream>>>(H1, W2, b2, zbuf);

    for (int t = 0; t < T_ITERS; ++t) {
        if (t == 0)
            k_pm_proj<S, false><<<B_N / 32, 256, 0, stream>>>(
                centers, mus, projW, projb, zbuf, hB, hTb, pAcc, pDen);
        else
            k_pm_proj<S, true><<<B_N / 32, 256, 0, stream>>>(
                centers, mus, projW, projb, zbuf, hB, hTb, pAcc, pDen);
        k_lateral<S><<<dim3(TILES, S), 128, 0, stream>>>(zbuf, hTb, pAcc, pDen);
    }

    k_logits_h<S><<<TILES, 256, 0, stream>>>(hB, pAcc, pDen, roW, rob,
                                             out_logits, out_h);
    hipMemcpyAsync(out_z, zbuf, (size_t)B_N * DL * sizeof(float),
                   hipMemcpyDeviceToDevice, stream);
}

extern "C" void kernel_launch(void* const* d_in, const int* in_sizes, int n_in,
                              void* d_out, int out_size, void* d_ws, size_t ws_size,
                              hipStream_t stream)
{
    const float* x       = (const float*)d_in[0];
    const float* W1      = (const float*)d_in[1];
    const float* b1      = (const float*)d_in[2];
    const float* W2      = (const float*)d_in[3];
    const float* b2      = (const float*)d_in[4];
    const float* centers = (const float*)d_in[5];
    const float* mus     = (const float*)d_in[6];
    const float* projW   = (const float*)d_in[7];
    const float* projb   = (const float*)d_in[8];
    const float* roW     = (const float*)d_in[9];
    const float* rob     = (const float*)d_in[10];

    float* ws  = (float*)d_ws;
    float* out = (float*)d_out;

    const size_t needS8 = ((size_t)8*B_N*CH + 8*B_N + B_N*DL + B_N*CH + B_N*CH/2) * 4;
    const size_t needS4 = ((size_t)4*B_N*CH + 4*B_N + B_N*DL + B_N*CH + B_N*CH/2) * 4;

    if (ws_size >= needS8)
        run_all<8>(x, W1, b1, W2, b2, centers, mus, projW, projb, roW, rob, ws, out, stream);
    else if (ws_size >= needS4)
        run_all<4>(x, W1, b1, W2, b2, centers, mus, projW, projb, roW, rob, ws, out, stream);
    else
        run_all<2>(x, W1, b1, W2, b2, centers, mus, projW, projb, roW, rob, ws, out, stream);
}

// Round 9
// 296.986 us; speedup vs baseline: 1.1070x; 1.0338x over previous
//
#include <hip/hip_runtime.h>
#include <hip/hip_bf16.h>
#include <math.h>

// ---- problem constants (fixed by setup_inputs) ----
#define B_N      8192
#define IN_DIM   784
#define HID      256
#define DL       8
#define NC       48
#define CH       64
#define NCLS     10
#define T_ITERS  5
#define TILES    128        // B_N / 64

#define DT_      0.12f
#define CLAMP_   3.0f
#define GAIN_    0.06f
// b = log2(e)/(2*sigma_i^2) = 0.50093578 ; sigma_e = sigma_i/2 -> E-exp = 4x I-exp.
// u = sqrt(b)*z ; Gram MFMA computes out = <ui,uj> - |ui|^2/2 - |uj|^2/2
// = -0.5*b*dist2 -> e1 = exp2(out); Ki-term = e1^2, Ke-term = e1^8.
#define SQIL2    0.70776814f
#define ONE_BF16 0x3F80u

#if defined(__has_builtin)
#if __has_builtin(__builtin_amdgcn_exp2f)
#define EXP2(x) __builtin_amdgcn_exp2f(x)
#endif
#endif
#ifndef EXP2
#define EXP2(x) exp2f(x)
#endif

typedef __attribute__((ext_vector_type(8))) short short8v;  // 8 bf16 (4 VGPRs)
typedef __attribute__((ext_vector_type(4))) float f32x4;    // MFMA C/D frag

__device__ __forceinline__ unsigned int pack_bf16_rhu(float lo, float hi) {
    unsigned int b0 = __builtin_bit_cast(unsigned int, lo);
    unsigned int b1 = __builtin_bit_cast(unsigned int, hi);
    return ((b0 + 0x8000u) >> 16) | ((b1 + 0x8000u) & 0xFFFF0000u);
}
__device__ __forceinline__ unsigned short bf16_1(float x) {
    return (unsigned short)((__builtin_bit_cast(unsigned int, x) + 0x8000u) >> 16);
}
__device__ __forceinline__ float bf16_to_f(unsigned short h) {
    return __builtin_bit_cast(float, ((unsigned int)h) << 16);
}

// split one z row (scaled) into hi/lo bf16 + c constant pair
__device__ __forceinline__ void z_split(const float4 a, const float4 b,
                                        uint4& Whi, uint4& Wlo, unsigned int& Wc)
{
    float u[8] = {SQIL2*a.x, SQIL2*a.y, SQIL2*a.z, SQIL2*a.w,
                  SQIL2*b.x, SQIL2*b.y, SQIL2*b.z, SQIL2*b.w};
    float sq = 0.f;
    #pragma unroll
    for (int d = 0; d < 8; ++d) sq = fmaf(u[d], u[d], sq);
    float cn = -0.5f * sq;
    unsigned short hi[8]; float lo[8];
    #pragma unroll
    for (int d = 0; d < 8; ++d) {
        hi[d] = bf16_1(u[d]);
        lo[d] = u[d] - bf16_to_f(hi[d]);
    }
    unsigned short ch_ = bf16_1(cn);
    unsigned short cl_ = bf16_1(cn - bf16_to_f(ch_));
    Whi.x = (unsigned int)hi[0] | ((unsigned int)hi[1] << 16);
    Whi.y = (unsigned int)hi[2] | ((unsigned int)hi[3] << 16);
    Whi.z = (unsigned int)hi[4] | ((unsigned int)hi[5] << 16);
    Whi.w = (unsigned int)hi[6] | ((unsigned int)hi[7] << 16);
    Wlo.x = pack_bf16_rhu(lo[0], lo[1]); Wlo.y = pack_bf16_rhu(lo[2], lo[3]);
    Wlo.z = pack_bf16_rhu(lo[4], lo[5]); Wlo.w = pack_bf16_rhu(lo[6], lo[7]);
    Wc = (unsigned int)ch_ | ((unsigned int)cl_ << 16);
}

// ============ encoder GEMM1: H1 = tanh(x @ W1 + b1) ============
// 64x64/4x4 body, 1-barrier double-buffered LDS (round-8 measured best).
__global__ __launch_bounds__(256) void k_gemm1_tanh(
    const float* __restrict__ x, const float* __restrict__ W1,
    const float* __restrict__ b1, float* __restrict__ H1)
{
    __shared__ float As[2][16][68];   // [buf][k][m], padded
    __shared__ float Bs[2][16][64];   // [buf][k][n]
    const int tid = threadIdx.x;
    const int row0 = blockIdx.x * 64;
    const int col0 = blockIdx.y * 64;
    const int tr = tid >> 4, tc = tid & 15;
    const int am = tid >> 2, akq = tid & 3;       // A staging role
    const int bkk = tid >> 4, bn4 = tid & 15;     // B staging role
    float acc[4][4] = {};

    // prologue: stage k-tile 0 into buffer 0
    {
        float4 va = *(const float4*)(x + (size_t)(row0 + am) * IN_DIM + akq * 4);
        float4 vb = *(const float4*)(W1 + (size_t)bkk * HID + col0 + bn4 * 4);
        As[0][akq*4+0][am] = va.x; As[0][akq*4+1][am] = va.y;
        As[0][akq*4+2][am] = va.z; As[0][akq*4+3][am] = va.w;
        *(float4*)(&Bs[0][bkk][bn4*4]) = vb;
    }

    const int NK = IN_DIM / 16;   // 49
    #pragma unroll 1
    for (int ks = 0; ks < NK; ++ks) {
        const int cur = ks & 1;
        const bool more = (ks + 1 < NK);
        float4 va, vb;
        if (more) {
            const int k0 = (ks + 1) * 16;
            va = *(const float4*)(x + (size_t)(row0 + am) * IN_DIM + k0 + akq * 4);
            vb = *(const float4*)(W1 + (size_t)(k0 + bkk) * HID + col0 + bn4 * 4);
        }
        __syncthreads();   // buffer[cur] fully written
        #pragma unroll
        for (int kk = 0; kk < 16; ++kk) {
            float4 a = *(const float4*)(&As[cur][kk][tr*4]);
            float4 b = *(const float4*)(&Bs[cur][kk][tc*4]);
            float av[4] = {a.x, a.y, a.z, a.w};
            float bv[4] = {b.x, b.y, b.z, b.w};
            #pragma unroll
            for (int i = 0; i < 4; ++i)
                #pragma unroll
                for (int j = 0; j < 4; ++j)
                    acc[i][j] += av[i] * bv[j];
        }
        if (more) {   // write next tile into the other buffer (no 2nd barrier:
            const int nb = cur ^ 1;   // nobody reads buf[nb] until next barrier)
            As[nb][akq*4+0][am] = va.x; As[nb][akq*4+1][am] = va.y;
            As[nb][akq*4+2][am] = va.z; As[nb][akq*4+3][am] = va.w;
            *(float4*)(&Bs[nb][bkk][bn4*4]) = vb;
        }
    }

    const float4 b1c = *(const float4*)(b1 + col0 + tc * 4);
    const float bb[4] = {b1c.x, b1c.y, b1c.z, b1c.w};
    #pragma unroll
    for (int i = 0; i < 4; ++i) {
        int r = row0 + tr*4 + i;
        float4 hv;
        hv.x = tanhf(acc[i][0] + bb[0]);
        hv.y = tanhf(acc[i][1] + bb[1]);
        hv.z = tanhf(acc[i][2] + bb[2]);
        hv.w = tanhf(acc[i][3] + bb[3]);
        *(float4*)(H1 + (size_t)r * HID + col0 + tc * 4) = hv;
    }
}

// ============ GEMM2: z0 = H1 @ W2 + b2 ============
__global__ __launch_bounds__(256) void k_gemm2(
    const float* __restrict__ H1, const float* __restrict__ W2,
    const float* __restrict__ b2, float* __restrict__ zbuf)
{
    __shared__ float W2s[HID][DL];
    const int tid = threadIdx.x;
    for (int l = tid; l < HID * DL; l += 256) W2s[l >> 3][l & 7] = W2[l];
    __syncthreads();
    const int row = blockIdx.x * 32 + (tid >> 3);
    const int d = tid & 7;
    float acc = b2[d];
    const float* hr = H1 + (size_t)row * HID;
    for (int k = 0; k < HID; k += 4) {
        float4 hv = *(const float4*)(hr + k);
        acc += hv.x * W2s[k][d] + hv.y * W2s[k+1][d]
             + hv.z * W2s[k+2][d] + hv.w * W2s[k+3][d];
    }
    zbuf[(size_t)row * DL + d] = acc;
}

// ============ PM field (4 steps) + fused partial-reduce + proj h-update ======
// 16 lanes/row (3 centers/lane): 131072 threads = 2 waves/SIMD (was 1).
// Reassociation only — exact IEEE sqrt/divide kept (amplification ~x200:
// 1-ulp reassoc noise invisible, approximate intrinsics still forbidden).
template<int S, bool HP>
__global__ __launch_bounds__(256) void k_pm_proj(
    const float* __restrict__ centers, const float* __restrict__ mus,
    const float* __restrict__ projW, const float* __restrict__ projb,
    float* __restrict__ zbuf, float* __restrict__ hB,
    unsigned short* __restrict__ hTb,
    const float* __restrict__ pAcc, const float* __restrict__ pDen)
{
    __shared__ float4 cs4[NC][2];
    __shared__ float mu_s[NC];
    __shared__ float pW[DL][CH];
    __shared__ float pb[CH];
    const int tid = threadIdx.x;
    for (int l = tid; l < NC * 2; l += 256) cs4[l >> 1][l & 1] = ((const float4*)centers)[l];
    if (tid < NC) mu_s[tid] = mus[tid];
    for (int l = tid; l < DL * CH; l += 256) pW[l >> 6][l & 63] = projW[l];
    if (tid < CH) pb[tid] = projb[tid];
    __syncthreads();

    const int rloc = tid >> 4;       // 0..15 rows per block
    const int ln   = tid & 15;       // 16 lanes per row
    const int row  = blockIdx.x * 16 + rloc;

    // lane ln handles centers ln, ln+16, ln+32
    float4 cza[3], czb[3];
    float mur[3];
    #pragma unroll
    for (int k = 0; k < 3; ++k) {
        cza[k] = cs4[ln + 16*k][0];
        czb[k] = cs4[ln + 16*k][1];
        mur[k] = mu_s[ln + 16*k];
    }

    float z[8];
    {
        const float4* zp = (const float4*)(zbuf + (size_t)row * DL);
        float4 a = zp[0], b = zp[1];
        z[0]=a.x; z[1]=a.y; z[2]=a.z; z[3]=a.w;
        z[4]=b.x; z[5]=b.y; z[6]=b.z; z[7]=b.w;
    }

    #pragma unroll
    for (int step = 0; step < 4; ++step) {
        float np = 0.f;
        float gp[8] = {0,0,0,0,0,0,0,0};
        #pragma unroll
        for (int k = 0; k < 3; ++k) {
            float d0 = z[0]-cza[k].x, d1 = z[1]-cza[k].y;
            float d2 = z[2]-cza[k].z, d3 = z[3]-cza[k].w;
            float d4 = z[4]-czb[k].x, d5 = z[5]-czb[k].y;
            float d6 = z[6]-czb[k].z, d7 = z[7]-czb[k].w;
            float r2 = 1e-4f;
            r2 = fmaf(d0,d0,r2); r2 = fmaf(d1,d1,r2);
            r2 = fmaf(d2,d2,r2); r2 = fmaf(d3,d3,r2);
            r2 = fmaf(d4,d4,r2); r2 = fmaf(d5,d5,r2);
            r2 = fmaf(d6,d6,r2); r2 = fmaf(d7,d7,r2);
            float r = sqrtf(r2);
            float mr = mur[k] / r;          // IEEE divide (exact)
            np += mr;
            float t = mr / r2;              // mu / (r*r2), IEEE
            gp[0] = fmaf(-t, d0, gp[0]); gp[1] = fmaf(-t, d1, gp[1]);
            gp[2] = fmaf(-t, d2, gp[2]); gp[3] = fmaf(-t, d3, gp[3]);
            gp[4] = fmaf(-t, d4, gp[4]); gp[5] = fmaf(-t, d5, gp[5]);
            gp[6] = fmaf(-t, d6, gp[6]); gp[7] = fmaf(-t, d7, gp[7]);
        }
        // butterfly across the 16 lanes of this row
        #pragma unroll
        for (int m = 1; m < 16; m <<= 1) {
            np += __shfl_xor(np, m);
            #pragma unroll
            for (int d = 0; d < 8; ++d) gp[d] += __shfl_xor(gp[d], m);
        }
        float s = DT_ / (1.f + np);         // IEEE divide
        #pragma unroll
        for (int d = 0; d < 8; ++d) {
            z[d] = fmaf(s, gp[d], z[d]);
            z[d] = fminf(fmaxf(z[d], -CLAMP_), CLAMP_);
        }
    }

    if (ln < 8) {   // lane ln writes z element ln
        float zout = z[0];
        #pragma unroll
        for (int d = 1; d < 8; ++d) zout = (ln == d) ? z[d] : zout;
        zbuf[(size_t)row * DL + ln] = zout;
    }

    // ---- h_in (fused reduce of split partials), then h_mid; 4 ch/lane ----
    const int c0 = ln * 4;
    float hin[4];
    if (HP) {
        float den = 1e-6f;
        #pragma unroll
        for (int s = 0; s < S; ++s) den += pDen[s * B_N + row];
        float inv = GAIN_ / den;
        float4 a = {0.f, 0.f, 0.f, 0.f};
        #pragma unroll
        for (int s = 0; s < S; ++s) {
            float4 p = *(const float4*)(pAcc + (size_t)s * B_N * CH
                                        + (size_t)row * CH + c0);
            a.x += p.x; a.y += p.y; a.z += p.z; a.w += p.w;
        }
        float4 hm = *(const float4*)(hB + (size_t)row * CH + c0);
        hin[0] = fmaf(inv, a.x, hm.x);
        hin[1] = fmaf(inv, a.y, hm.y);
        hin[2] = fmaf(inv, a.z, hm.z);
        hin[3] = fmaf(inv, a.w, hm.w);
    } else {
        #pragma unroll
        for (int k = 0; k < 4; ++k) hin[k] = 0.f;
    }
    #pragma unroll
    for (int k = 0; k < 4; ++k) {
        int c = c0 + k;
        float s = pb[c];
        #pragma unroll
        for (int dd = 0; dd < DL; ++dd) s = fmaf(z[dd], pW[dd][c], s);
        hin[k] = 0.9f * hin[k] + 0.1f * tanhf(s);
    }
    float4 o0 = {hin[0], hin[1], hin[2], hin[3]};
    *(float4*)(hB + (size_t)row * CH + c0) = o0;

    // sigma-permuted transposed bf16 h_mid for lateral staging
    {
        const int jl = row & 63;
        const int colp = (jl & 35) | ((jl & 12) << 1) | ((jl & 16) >> 2);
        const size_t tb = (size_t)(row & ~63) + colp;
        #pragma unroll
        for (int k = 0; k < 4; ++k)
            hTb[(size_t)(c0 + k) * B_N + tb] = bf16_1(hin[k]);
    }
}

// ============ lateral EI: Gram-MFMA weights + MFMA K@h (round-6 structure) ===
// 256 threads = 4 waves, 16 i/wave (measured best); single barrier per tile
// (double-buffer: writes to buf[nb] can't race reads of buf[cur]) + setprio
// around the MFMA clusters.
template<int S>
__global__ __launch_bounds__(256, 4) void k_lateral(
    const float* __restrict__ zbuf, const unsigned short* __restrict__ hTb,
    float* __restrict__ pAcc, float* __restrict__ pDen)
{
    __shared__ __align__(16) unsigned short zA[2][64 * 24]; // 48B rows: hi|lo|aux
    __shared__ __align__(16) unsigned short hsT[2][CH][72]; // h^T bf16 (perm cols)
    const int tid  = threadIdx.x;
    const int lane = tid & 63;
    const int wv   = tid >> 6;
    const int l15  = lane & 15;
    const int g    = lane >> 4;
    const int rowbase = blockIdx.x * 64;
    const int t0 = (TILES * blockIdx.y) / S;
    const int t1 = (TILES * (blockIdx.y + 1)) / S;
    const int chS = tid >> 2, segS = tid & 3;   // h staging role

    // ---- per-lane Gram B-frag (own i-row) ----
    short8v bZ;
    {
        const int irow = rowbase + 16 * wv + l15;
        const float4* zp = (const float4*)(zbuf + (size_t)irow * DL);
        uint4 Whi, Wlo; unsigned int Wc;
        z_split(zp[0], zp[1], Whi, Wlo, Wc);
        union { unsigned int u[4]; short8v v; } uh, ul, ua;
        uh.u[0]=Whi.x; uh.u[1]=Whi.y; uh.u[2]=Whi.z; uh.u[3]=Whi.w;
        ul.u[0]=Wlo.x; ul.u[1]=Wlo.y; ul.u[2]=Wlo.z; ul.u[3]=Wlo.w;
        ua.u[0] = ONE_BF16 | (ONE_BF16 << 16);
        ua.u[1] = Wc; ua.u[2] = 0; ua.u[3] = 0;
        bZ = (g == 2) ? ul.v : ((g == 3) ? ua.v : uh.v);
    }
    const int offsh = (g == 1) ? 8 : ((g == 3) ? 16 : 0);

    short8v bones;
    {
        union { unsigned int u[4]; short8v v; } uo;
        uo.u[0] = uo.u[1] = uo.u[2] = uo.u[3] = ONE_BF16 | (ONE_BF16 << 16);
        bones = uo.v;
    }

    f32x4 acc0 = {0,0,0,0}, acc1 = {0,0,0,0}, acc2 = {0,0,0,0}, acc3 = {0,0,0,0};
    f32x4 acc4 = {0,0,0,0};
    const f32x4 zc = {0,0,0,0};

    // ---- prologue: stage tile t0 into buffer 0 ----
    {
        const int jb = t0 * 64;
        if (tid < 64) {
            const float4* zp = (const float4*)(zbuf + (size_t)(jb + tid) * DL);
            uint4 Whi, Wlo; unsigned int Wc;
            z_split(zp[0], zp[1], Whi, Wlo, Wc);
            uint4 W2v; W2v.x = Wc; W2v.y = ONE_BF16 | (ONE_BF16 << 16);
            W2v.z = 0; W2v.w = 0;
            unsigned short* dst = &zA[0][tid * 24];
            *(uint4*)(dst)      = Whi;
            *(uint4*)(dst + 8)  = Wlo;
            *(uint4*)(dst + 16) = W2v;
        }
        const unsigned short* hs = hTb + (size_t)chS * B_N + jb + segS * 16;
        *(uint4*)(&hsT[0][chS][segS * 16])     = *(const uint4*)(hs);
        *(uint4*)(&hsT[0][chS][segS * 16 + 8]) = *(const uint4*)(hs + 8);
    }

    #pragma unroll 1
    for (int jt = t0; jt < t1; ++jt) {
        const int cur = (jt - t0) & 1;
        const bool more = (jt + 1 < t1);
        uint4 h0n, h1n;
        float4 zna, znb;
        if (more) {
            const int jb2 = (jt + 1) * 64;
            const unsigned short* hs = hTb + (size_t)chS * B_N + jb2 + segS * 16;
            h0n = *(const uint4*)(hs);
            h1n = *(const uint4*)(hs + 8);
            if (tid < 64) {
                const float4* zp = (const float4*)(zbuf + (size_t)(jb2 + tid) * DL);
                zna = zp[0]; znb = zp[1];
            }
        }
        __syncthreads();   // buffer[cur] ready (single barrier per tile)

        // ---- Gram: 4 MFMAs -> gac[t][r] = out for (i=l15, j=16t+4g+r) ----
        f32x4 gac[4];
        __builtin_amdgcn_s_setprio(1);
        #pragma unroll
        for (int t = 0; t < 4; ++t) {
            short8v az = *(const short8v*)(&zA[cur][(t * 16 + l15) * 24 + offsh]);
            gac[t] = __builtin_amdgcn_mfma_f32_16x16x32_bf16(az, bZ, zc, 0, 0, 0);
        }
        __builtin_amdgcn_s_setprio(0);

        // ---- w path: A-slot (kb,m) <- gac[2kb + (m>>2)][m&3], lane-local ----
        short8v afr[2];
        #pragma unroll
        for (int kb = 0; kb < 2; ++kb) {
            float w8[8];
            #pragma unroll
            for (int m = 0; m < 8; ++m) {
                float out = gac[2 * kb + (m >> 2)][m & 3];
                float e1 = EXP2(out);
                float e2 = e1 * e1;
                float e4 = e2 * e2;
                float e8 = e4 * e4;
                w8[m] = fmaf(0.8f, e8, -e2);
            }
            union { unsigned int u[4]; short8v v; } uf;
            uf.u[0] = pack_bf16_rhu(w8[0], w8[1]);
            uf.u[1] = pack_bf16_rhu(w8[2], w8[3]);
            uf.u[2] = pack_bf16_rhu(w8[4], w8[5]);
            uf.u[3] = pack_bf16_rhu(w8[6], w8[7]);
            afr[kb] = uf.v;
        }

        // ---- K@h + den ----
        __builtin_amdgcn_s_setprio(1);
        #pragma unroll
        for (int kb = 0; kb < 2; ++kb) {
            const int jo = kb * 32 + g * 8;
            short8v b0 = *(const short8v*)&hsT[cur][ 0 + l15][jo];
            short8v b1 = *(const short8v*)&hsT[cur][16 + l15][jo];
            short8v b2 = *(const short8v*)&hsT[cur][32 + l15][jo];
            short8v b3 = *(const short8v*)&hsT[cur][48 + l15][jo];
            acc0 = __builtin_amdgcn_mfma_f32_16x16x32_bf16(afr[kb], b0, acc0, 0, 0, 0);
            acc1 = __builtin_amdgcn_mfma_f32_16x16x32_bf16(afr[kb], b1, acc1, 0, 0, 0);
            acc2 = __builtin_amdgcn_mfma_f32_16x16x32_bf16(afr[kb], b2, acc2, 0, 0, 0);
            acc3 = __builtin_amdgcn_mfma_f32_16x16x32_bf16(afr[kb], b3, acc3, 0, 0, 0);
            acc4 = __builtin_amdgcn_mfma_f32_16x16x32_bf16(afr[kb], bones, acc4, 0, 0, 0);
        }
        __builtin_amdgcn_s_setprio(0);

        // ---- write staged regs into buffer[cur^1] (no 2nd barrier needed) ----
        if (more) {
            const int nb = cur ^ 1;
            if (tid < 64) {
                uint4 Whi, Wlo; unsigned int Wc;
                z_split(zna, znb, Whi, Wlo, Wc);
                uint4 W2v; W2v.x = Wc; W2v.y = ONE_BF16 | (ONE_BF16 << 16);
                W2v.z = 0; W2v.w = 0;
                unsigned short* dst = &zA[nb][tid * 24];
                *(uint4*)(dst)      = Whi;
                *(uint4*)(dst + 8)  = Wlo;
                *(uint4*)(dst + 16) = W2v;
            }
            *(uint4*)(&hsT[nb][chS][segS * 16])     = h0n;
            *(uint4*)(&hsT[nb][chS][segS * 16 + 8]) = h1n;
        }
    }

    // ---- epilogue: partial acc + den ----
    float* pA = pAcc + (size_t)blockIdx.y * (B_N * CH) + (size_t)rowbase * CH;
    #pragma unroll
    for (int r = 0; r < 4; ++r) {
        int gi = 16 * wv + g * 4 + r;
        pA[(size_t)gi * CH +  0 + l15] = acc0[r];
        pA[(size_t)gi * CH + 16 + l15] = acc1[r];
        pA[(size_t)gi * CH + 32 + l15] = acc2[r];
        pA[(size_t)gi * CH + 48 + l15] = acc3[r];
    }
    if (l15 == 0) {
        #pragma unroll
        for (int r = 0; r < 4; ++r)
            pDen[blockIdx.y * B_N + rowbase + 16 * wv + g * 4 + r] = acc4[r];
    }
}

// ============ final: h = hmid + GAIN*acc/den ; logits = h @ roW + rob ======
template<int S>
__global__ __launch_bounds__(256) void k_logits_h(
    const float* __restrict__ hmid, const float* __restrict__ pAcc,
    const float* __restrict__ pDen, const float* __restrict__ roW,
    const float* __restrict__ rob, float* __restrict__ out_logits,
    float* __restrict__ out_h)
{
    __shared__ float hsh[64][68];
    __shared__ float ro[CH][NCLS];
    __shared__ float rb[NCLS];
    const int tid = threadIdx.x;
    for (int l = tid; l < CH * NCLS; l += 256) ro[l / NCLS][l % NCLS] = roW[l];
    if (tid < NCLS) rb[tid] = rob[tid];
    const int rowbase = blockIdx.x * 64;
    const int r  = tid >> 2;
    const int c0 = (tid & 3) * 16;
    const int row = rowbase + r;
    float den = 1e-6f;
    #pragma unroll
    for (int s = 0; s < S; ++s) den += pDen[s * B_N + row];
    float inv = GAIN_ / den;
    #pragma unroll
    for (int q = 0; q < 4; ++q) {
        float4 a = {0.f, 0.f, 0.f, 0.f};
        #pragma unroll
        for (int s = 0; s < S; ++s) {
            float4 p = *(const float4*)(pAcc + (size_t)s * B_N * CH
                                        + (size_t)row * CH + c0 + q * 4);
            a.x += p.x; a.y += p.y; a.z += p.z; a.w += p.w;
        }
        float4 hm = *(const float4*)(hmid + (size_t)row * CH + c0 + q * 4);
        float4 hv;
        hv.x = fmaf(inv, a.x, hm.x); hv.y = fmaf(inv, a.y, hm.y);
        hv.z = fmaf(inv, a.z, hm.z); hv.w = fmaf(inv, a.w, hm.w);
        *(float4*)(&hsh[r][c0 + q * 4]) = hv;
        *(float4*)(out_h + (size_t)row * CH + c0 + q * 4) = hv;
    }
    __syncthreads();
    for (int idx = tid; idx < 64 * NCLS; idx += 256) {
        int rr = idx / NCLS, o = idx % NCLS;
        float s = rb[o];
        #pragma unroll
        for (int k = 0; k < CH; ++k) s = fmaf(hsh[rr][k], ro[k][o], s);
        out_logits[(size_t)(rowbase + rr) * NCLS + o] = s;
    }
}

// ---- per-split launch helper ----
template<int S>
static void run_all(const float* x, const float* W1, const float* b1,
                    const float* W2, const float* b2, const float* centers,
                    const float* mus, const float* projW, const float* projb,
                    const float* roW, const float* rob,
                    float* ws, float* out, hipStream_t stream)
{
    float* pAcc = ws;
    float* pDen = ws + (size_t)S * B_N * CH;
    float* zbuf = pDen + (size_t)S * B_N;
    float* hB   = zbuf + B_N * DL;
    unsigned short* hTb = (unsigned short*)(hB + B_N * CH);   // B_N*CH bf16
    float* H1   = ws;   // pre-loop only; fits under pAcc (S >= 4)

    float* out_logits = out;
    float* out_z      = out + 81920;
    float* out_h      = out_z + 65536;

    k_gemm1_tanh<<<dim3(B_N / 64, HID / 64), 256, 0, stream>>>(x, W1, b1, H1);
    k_gemm2<<<B_N / 32, 256, 0, stream>>>(H1, W2, b2, zbuf);

    for (int t = 0; t < T_ITERS; ++t) {
        if (t == 0)
            k_pm_proj<S, false><<<B_N / 16, 256, 0, stream>>>(
                centers, mus, projW, projb, zbuf, hB, hTb, pAcc, pDen);
        else
            k_pm_proj<S, true><<<B_N / 16, 256, 0, stream>>>(
                centers, mus, projW, projb, zbuf, hB, hTb, pAcc, pDen);
        k_lateral<S><<<dim3(TILES, S), 256, 0, stream>>>(zbuf, hTb, pAcc, pDen);
    }

    k_logits_h<S><<<TILES, 256, 0, stream>>>(hB, pAcc, pDen, roW, rob,
                                             out_logits, out_h);
    hipMemcpyAsync(out_z, zbuf, (size_t)B_N * DL * sizeof(float),
                   hipMemcpyDeviceToDevice, stream);
}

extern "C" void kernel_launch(void* const* d_in, const int* in_sizes, int n_in,
                              void* d_out, int out_size, void* d_ws, size_t ws_size,
                              hipStream_t stream)
{
    const float* x       = (const float*)d_in[0];
    const float* W1      = (const float*)d_in[1];
    const float* b1      = (const float*)d_in[2];
    const float* W2      = (const float*)d_in[3];
    const float* b2      = (const float*)d_in[4];
    const float* centers = (const float*)d_in[5];
    const float* mus     = (const float*)d_in[6];
    const float* projW   = (const float*)d_in[7];
    const float* projb   = (const float*)d_in[8];
    const float* roW     = (const float*)d_in[9];
    const float* rob     = (const float*)d_in[10];

    float* ws  = (float*)d_ws;
    float* out = (float*)d_out;

    const size_t needS8 = ((size_t)8*B_N*CH + 8*B_N + B_N*DL + B_N*CH + B_N*CH/2) * 4;
    const size_t needS4 = ((size_t)4*B_N*CH + 4*B_N + B_N*DL + B_N*CH + B_N*CH/2) * 4;

    if (ws_size >= needS8)
        run_all<8>(x, W1, b1, W2, b2, centers, mus, projW, projb, roW, rob, ws, out, stream);
    else if (ws_size >= needS4)
        run_all<4>(x, W1, b1, W2, b2, centers, mus, projW, projb, roW, rob, ws, out, stream);
    else
        run_all<2>(x, W1, b1, W2, b2, centers, mus, projW, projb, roW, rob, ws, out, stream);
}

// Round 11
// 278.134 us; speedup vs baseline: 1.1820x; 1.0678x over previous
//
#include <hip/hip_runtime.h>
#include <hip/hip_bf16.h>
#include <math.h>

// ---- problem constants (fixed by setup_inputs) ----
#define B_N      8192
#define IN_DIM   784
#define KPAD     800        // 25 k-tiles of 32, zero-padded
#define HID      256
#define DL       8
#define NC       48
#define CH       64
#define NCLS     10
#define T_ITERS  5
#define TILES    128        // B_N / 64

#define DT_      0.12f
#define CLAMP_   3.0f
#define GAIN_    0.06f
// b = log2(e)/(2*sigma_i^2) = 0.50093578 ; sigma_e = sigma_i/2 -> E-exp = 4x I-exp.
#define SQIL2    0.70776814f
#define ONE_BF16 0x3F80u

#if defined(__has_builtin)
#if __has_builtin(__builtin_amdgcn_exp2f)
#define EXP2(x) __builtin_amdgcn_exp2f(x)
#endif
#endif
#ifndef EXP2
#define EXP2(x) exp2f(x)
#endif

typedef __attribute__((ext_vector_type(8))) short short8v;  // 8 bf16 (4 VGPRs)
typedef __attribute__((ext_vector_type(4))) float f32x4;    // MFMA C/D frag

__device__ __forceinline__ unsigned int pack_bf16_rhu(float lo, float hi) {
    unsigned int b0 = __builtin_bit_cast(unsigned int, lo);
    unsigned int b1 = __builtin_bit_cast(unsigned int, hi);
    return ((b0 + 0x8000u) >> 16) | ((b1 + 0x8000u) & 0xFFFF0000u);
}
__device__ __forceinline__ unsigned short bf16_1(float x) {
    return (unsigned short)((__builtin_bit_cast(unsigned int, x) + 0x8000u) >> 16);
}
__device__ __forceinline__ float bf16_to_f(unsigned short h) {
    return __builtin_bit_cast(float, ((unsigned int)h) << 16);
}

// split one z row (scaled) into hi/lo bf16 + c constant pair (lateral path)
__device__ __forceinline__ void z_split(const float4 a, const float4 b,
                                        uint4& Whi, uint4& Wlo, unsigned int& Wc)
{
    float u[8] = {SQIL2*a.x, SQIL2*a.y, SQIL2*a.z, SQIL2*a.w,
                  SQIL2*b.x, SQIL2*b.y, SQIL2*b.z, SQIL2*b.w};
    float sq = 0.f;
    #pragma unroll
    for (int d = 0; d < 8; ++d) sq = fmaf(u[d], u[d], sq);
    float cn = -0.5f * sq;
    unsigned short hi[8]; float lo[8];
    #pragma unroll
    for (int d = 0; d < 8; ++d) {
        hi[d] = bf16_1(u[d]);
        lo[d] = u[d] - bf16_to_f(hi[d]);
    }
    unsigned short ch_ = bf16_1(cn);
    unsigned short cl_ = bf16_1(cn - bf16_to_f(ch_));
    Whi.x = (unsigned int)hi[0] | ((unsigned int)hi[1] << 16);
    Whi.y = (unsigned int)hi[2] | ((unsigned int)hi[3] << 16);
    Whi.z = (unsigned int)hi[4] | ((unsigned int)hi[5] << 16);
    Whi.w = (unsigned int)hi[6] | ((unsigned int)hi[7] << 16);
    Wlo.x = pack_bf16_rhu(lo[0], lo[1]); Wlo.y = pack_bf16_rhu(lo[2], lo[3]);
    Wlo.z = pack_bf16_rhu(lo[4], lo[5]); Wlo.w = pack_bf16_rhu(lo[6], lo[7]);
    Wc = (unsigned int)ch_ | ((unsigned int)cl_ << 16);
}

// 3-term bf16 split of 8 f32 values (24 mantissa bits -> near-exact)
__device__ __forceinline__ void split3_8(const float v[8],
                                         uint4& Th, uint4& Tm, uint4& Tl)
{
    unsigned short h8[8], m8[8], l8[8];
    #pragma unroll
    for (int d = 0; d < 8; ++d) {
        unsigned short h = bf16_1(v[d]);
        float r1 = v[d] - bf16_to_f(h);
        unsigned short m = bf16_1(r1);
        float r2 = r1 - bf16_to_f(m);
        unsigned short l = bf16_1(r2);
        h8[d] = h; m8[d] = m; l8[d] = l;
    }
    Th.x = (unsigned int)h8[0] | ((unsigned int)h8[1] << 16);
    Th.y = (unsigned int)h8[2] | ((unsigned int)h8[3] << 16);
    Th.z = (unsigned int)h8[4] | ((unsigned int)h8[5] << 16);
    Th.w = (unsigned int)h8[6] | ((unsigned int)h8[7] << 16);
    Tm.x = (unsigned int)m8[0] | ((unsigned int)m8[1] << 16);
    Tm.y = (unsigned int)m8[2] | ((unsigned int)m8[3] << 16);
    Tm.z = (unsigned int)m8[4] | ((unsigned int)m8[5] << 16);
    Tm.w = (unsigned int)m8[6] | ((unsigned int)m8[7] << 16);
    Tl.x = (unsigned int)l8[0] | ((unsigned int)l8[1] << 16);
    Tl.y = (unsigned int)l8[2] | ((unsigned int)l8[3] << 16);
    Tl.z = (unsigned int)l8[4] | ((unsigned int)l8[5] << 16);
    Tl.w = (unsigned int)l8[6] | ((unsigned int)l8[7] << 16);
}

// ============ one-time: W1 -> transposed 3-term bf16, k padded to 800 ========
__global__ __launch_bounds__(256) void k_w1split(
    const float* __restrict__ W1, unsigned short* __restrict__ W1aT,
    unsigned short* __restrict__ W1bT, unsigned short* __restrict__ W1cT)
{
    const int k = blockIdx.x;        // 0..799
    const int n = threadIdx.x;       // 0..255
    float v = (k < IN_DIM) ? W1[(size_t)k * HID + n] : 0.f;
    unsigned short h = bf16_1(v);
    float r1 = v - bf16_to_f(h);
    unsigned short m = bf16_1(r1);
    unsigned short l = bf16_1(r1 - bf16_to_f(m));
    W1aT[(size_t)n * KPAD + k] = h;
    W1bT[(size_t)n * KPAD + k] = m;
    W1cT[(size_t)n * KPAD + k] = l;
}

// ============ encoder GEMM1 via MFMA (3-term bf16 split, f32 accum) ==========
// x,w split to 24 mantissa bits; 6 product-pairs (>=2^-18) per n-tile ->
// z0 error ~1.5e-8; flow amplification ~1.6e4 (measured r10) -> ~2e-4 final.
// 64x64 block, 4 waves. 1-barrier double-buffered LDS (round-8 pattern).
__global__ __launch_bounds__(256, 2) void k_gemm1_tanh(
    const float* __restrict__ x, const unsigned short* __restrict__ W1aT,
    const unsigned short* __restrict__ W1bT, const unsigned short* __restrict__ W1cT,
    const float* __restrict__ b1, float* __restrict__ H1)
{
    __shared__ __align__(16) unsigned short Ah[2][64][40], Am[2][64][40], Al[2][64][40];
    __shared__ __align__(16) unsigned short Bh[2][64][40], Bm[2][64][40], Bl[2][64][40];
    const int tid = threadIdx.x;
    const int row0 = blockIdx.x * 64;
    const int col0 = blockIdx.y * 64;
    const int wv = tid >> 6, lane = tid & 63;
    const int l15 = lane & 15, g = lane >> 4;
    const int sr = tid >> 2, ss = tid & 3;   // staging: row/n = sr, 8-k seg = ss

    f32x4 acc[4] = {{0,0,0,0},{0,0,0,0},{0,0,0,0},{0,0,0,0}};

    // prologue: tile 0 -> buf 0
    {
        float xv[8];
        {
            const float* xp = x + (size_t)(row0 + sr) * IN_DIM + ss * 8;
            float4 a = *(const float4*)(xp), b = *(const float4*)(xp + 4);
            xv[0]=a.x; xv[1]=a.y; xv[2]=a.z; xv[3]=a.w;
            xv[4]=b.x; xv[5]=b.y; xv[6]=b.z; xv[7]=b.w;
        }
        uint4 Th, Tm, Tl;
        split3_8(xv, Th, Tm, Tl);
        *(uint4*)&Ah[0][sr][ss * 8] = Th;
        *(uint4*)&Am[0][sr][ss * 8] = Tm;
        *(uint4*)&Al[0][sr][ss * 8] = Tl;
        const size_t wo = (size_t)(col0 + sr) * KPAD + ss * 8;
        *(uint4*)&Bh[0][sr][ss * 8] = *(const uint4*)(W1aT + wo);
        *(uint4*)&Bm[0][sr][ss * 8] = *(const uint4*)(W1bT + wo);
        *(uint4*)&Bl[0][sr][ss * 8] = *(const uint4*)(W1cT + wo);
    }

    const int NK = KPAD / 32;   // 25
    #pragma unroll 1
    for (int ks = 0; ks < NK; ++ks) {
        const int cur = ks & 1;
        const bool more = (ks + 1 < NK);
        float xv[8];
        uint4 wa4, wb4, wc4;
        if (more) {
            const int k0 = (ks + 1) * 32;
            if (k0 + ss * 8 < IN_DIM) {
                const float* xp = x + (size_t)(row0 + sr) * IN_DIM + k0 + ss * 8;
                float4 a = *(const float4*)(xp), b = *(const float4*)(xp + 4);
                xv[0]=a.x; xv[1]=a.y; xv[2]=a.z; xv[3]=a.w;
                xv[4]=b.x; xv[5]=b.y; xv[6]=b.z; xv[7]=b.w;
            } else {
                #pragma unroll
                for (int d = 0; d < 8; ++d) xv[d] = 0.f;
            }
            const size_t wo = (size_t)(col0 + sr) * KPAD + k0 + ss * 8;
            wa4 = *(const uint4*)(W1aT + wo);
            wb4 = *(const uint4*)(W1bT + wo);
            wc4 = *(const uint4*)(W1cT + wo);
        }
        __syncthreads();   // buffer[cur] fully written

        short8v ah = *(const short8v*)&Ah[cur][16 * wv + l15][g * 8];
        short8v am = *(const short8v*)&Am[cur][16 * wv + l15][g * 8];
        short8v al = *(const short8v*)&Al[cur][16 * wv + l15][g * 8];
        __builtin_amdgcn_s_setprio(1);
        #pragma unroll
        for (int nt = 0; nt < 4; ++nt) {
            short8v bh = *(const short8v*)&Bh[cur][nt * 16 + l15][g * 8];
            short8v bm = *(const short8v*)&Bm[cur][nt * 16 + l15][g * 8];
            short8v bl = *(const short8v*)&Bl[cur][nt * 16 + l15][g * 8];
            acc[nt] = __builtin_amdgcn_mfma_f32_16x16x32_bf16(ah, bh, acc[nt], 0, 0, 0);
            acc[nt] = __builtin_amdgcn_mfma_f32_16x16x32_bf16(am, bh, acc[nt], 0, 0, 0);
            acc[nt] = __builtin_amdgcn_mfma_f32_16x16x32_bf16(ah, bm, acc[nt], 0, 0, 0);
            acc[nt] = __builtin_amdgcn_mfma_f32_16x16x32_bf16(al, bh, acc[nt], 0, 0, 0);
            acc[nt] = __builtin_amdgcn_mfma_f32_16x16x32_bf16(am, bm, acc[nt], 0, 0, 0);
            acc[nt] = __builtin_amdgcn_mfma_f32_16x16x32_bf16(ah, bl, acc[nt], 0, 0, 0);
        }
        __builtin_amdgcn_s_setprio(0);

        if (more) {   // write next tile into other buffer (no 2nd barrier)
            const int nb = cur ^ 1;
            uint4 Th, Tm, Tl;
            split3_8(xv, Th, Tm, Tl);
            *(uint4*)&Ah[nb][sr][ss * 8] = Th;
            *(uint4*)&Am[nb][sr][ss * 8] = Tm;
            *(uint4*)&Al[nb][sr][ss * 8] = Tl;
            *(uint4*)&Bh[nb][sr][ss * 8] = wa4;
            *(uint4*)&Bm[nb][sr][ss * 8] = wb4;
            *(uint4*)&Bl[nb][sr][ss * 8] = wc4;
        }
    }

    // epilogue: D[g*4+r][l15] per n-tile
    #pragma unroll
    for (int nt = 0; nt < 4; ++nt) {
        const int cc = col0 + nt * 16 + l15;
        const float bc = b1[cc];
        #pragma unroll
        for (int r = 0; r < 4; ++r) {
            const int rr = row0 + 16 * wv + g * 4 + r;
            H1[(size_t)rr * HID + cc] = tanhf(acc[nt][r] + bc);
        }
    }
}

// ============ GEMM2: z0 = H1 @ W2 + b2 ============
__global__ __launch_bounds__(256) void k_gemm2(
    const float* __restrict__ H1, const float* __restrict__ W2,
    const float* __restrict__ b2, float* __restrict__ zbuf)
{
    __shared__ float W2s[HID][DL];
    const int tid = threadIdx.x;
    for (int l = tid; l < HID * DL; l += 256) W2s[l >> 3][l & 7] = W2[l];
    __syncthreads();
    const int row = blockIdx.x * 32 + (tid >> 3);
    const int d = tid & 7;
    float acc = b2[d];
    const float* hr = H1 + (size_t)row * HID;
    for (int k = 0; k < HID; k += 4) {
        float4 hv = *(const float4*)(hr + k);
        acc += hv.x * W2s[k][d] + hv.y * W2s[k+1][d]
             + hv.z * W2s[k+2][d] + hv.w * W2s[k+3][d];
    }
    zbuf[(size_t)row * DL + d] = acc;
}

// ============ PM field (4 steps) + fused partial-reduce + proj h-update ======
// 16 lanes/row (3 centers/lane). Exact IEEE sqrt/divide in the stiff flow.
template<int S, bool HP>
__global__ __launch_bounds__(256) void k_pm_proj(
    const float* __restrict__ centers, const float* __restrict__ mus,
    const float* __restrict__ projW, const float* __restrict__ projb,
    float* __restrict__ zbuf, float* __restrict__ hB,
    unsigned short* __restrict__ hTb,
    const float* __restrict__ pAcc, const float* __restrict__ pDen)
{
    __shared__ float4 cs4[NC][2];
    __shared__ float mu_s[NC];
    __shared__ float pW[DL][CH];
    __shared__ float pb[CH];
    const int tid = threadIdx.x;
    for (int l = tid; l < NC * 2; l += 256) cs4[l >> 1][l & 1] = ((const float4*)centers)[l];
    if (tid < NC) mu_s[tid] = mus[tid];
    for (int l = tid; l < DL * CH; l += 256) pW[l >> 6][l & 63] = projW[l];
    if (tid < CH) pb[tid] = projb[tid];
    __syncthreads();

    const int rloc = tid >> 4;
    const int ln   = tid & 15;
    const int row  = blockIdx.x * 16 + rloc;

    float4 cza[3], czb[3];
    float mur[3];
    #pragma unroll
    for (int k = 0; k < 3; ++k) {
        cza[k] = cs4[ln + 16*k][0];
        czb[k] = cs4[ln + 16*k][1];
        mur[k] = mu_s[ln + 16*k];
    }

    float z[8];
    {
        const float4* zp = (const float4*)(zbuf + (size_t)row * DL);
        float4 a = zp[0], b = zp[1];
        z[0]=a.x; z[1]=a.y; z[2]=a.z; z[3]=a.w;
        z[4]=b.x; z[5]=b.y; z[6]=b.z; z[7]=b.w;
    }

    #pragma unroll
    for (int step = 0; step < 4; ++step) {
        float np = 0.f;
        float gp[8] = {0,0,0,0,0,0,0,0};
        #pragma unroll
        for (int k = 0; k < 3; ++k) {
            float d0 = z[0]-cza[k].x, d1 = z[1]-cza[k].y;
            float d2 = z[2]-cza[k].z, d3 = z[3]-cza[k].w;
            float d4 = z[4]-czb[k].x, d5 = z[5]-czb[k].y;
            float d6 = z[6]-czb[k].z, d7 = z[7]-czb[k].w;
            float r2 = 1e-4f;
            r2 = fmaf(d0,d0,r2); r2 = fmaf(d1,d1,r2);
            r2 = fmaf(d2,d2,r2); r2 = fmaf(d3,d3,r2);
            r2 = fmaf(d4,d4,r2); r2 = fmaf(d5,d5,r2);
            r2 = fmaf(d6,d6,r2); r2 = fmaf(d7,d7,r2);
            float r = sqrtf(r2);
            float mr = mur[k] / r;
            np += mr;
            float t = mr / r2;
            gp[0] = fmaf(-t, d0, gp[0]); gp[1] = fmaf(-t, d1, gp[1]);
            gp[2] = fmaf(-t, d2, gp[2]); gp[3] = fmaf(-t, d3, gp[3]);
            gp[4] = fmaf(-t, d4, gp[4]); gp[5] = fmaf(-t, d5, gp[5]);
            gp[6] = fmaf(-t, d6, gp[6]); gp[7] = fmaf(-t, d7, gp[7]);
        }
        #pragma unroll
        for (int m = 1; m < 16; m <<= 1) {
            np += __shfl_xor(np, m);
            #pragma unroll
            for (int d = 0; d < 8; ++d) gp[d] += __shfl_xor(gp[d], m);
        }
        float s = DT_ / (1.f + np);
        #pragma unroll
        for (int d = 0; d < 8; ++d) {
            z[d] = fmaf(s, gp[d], z[d]);
            z[d] = fminf(fmaxf(z[d], -CLAMP_), CLAMP_);
        }
    }

    if (ln < 8) {
        float zout = z[0];
        #pragma unroll
        for (int d = 1; d < 8; ++d) zout = (ln == d) ? z[d] : zout;
        zbuf[(size_t)row * DL + ln] = zout;
    }

    const int c0 = ln * 4;
    float hin[4];
    if (HP) {
        float den = 1e-6f;
        #pragma unroll
        for (int s = 0; s < S; ++s) den += pDen[s * B_N + row];
        float inv = GAIN_ / den;
        float4 a = {0.f, 0.f, 0.f, 0.f};
        #pragma unroll
        for (int s = 0; s < S; ++s) {
            float4 p = *(const float4*)(pAcc + (size_t)s * B_N * CH
                                        + (size_t)row * CH + c0);
            a.x += p.x; a.y += p.y; a.z += p.z; a.w += p.w;
        }
        float4 hm = *(const float4*)(hB + (size_t)row * CH + c0);
        hin[0] = fmaf(inv, a.x, hm.x);
        hin[1] = fmaf(inv, a.y, hm.y);
        hin[2] = fmaf(inv, a.z, hm.z);
        hin[3] = fmaf(inv, a.w, hm.w);
    } else {
        #pragma unroll
        for (int k = 0; k < 4; ++k) hin[k] = 0.f;
    }
    #pragma unroll
    for (int k = 0; k < 4; ++k) {
        int c = c0 + k;
        float s = pb[c];
        #pragma unroll
        for (int dd = 0; dd < DL; ++dd) s = fmaf(z[dd], pW[dd][c], s);
        hin[k] = 0.9f * hin[k] + 0.1f * tanhf(s);
    }
    float4 o0 = {hin[0], hin[1], hin[2], hin[3]};
    *(float4*)(hB + (size_t)row * CH + c0) = o0;

    {
        const int jl = row & 63;
        const int colp = (jl & 35) | ((jl & 12) << 1) | ((jl & 16) >> 2);
        const size_t tb = (size_t)(row & ~63) + colp;
        #pragma unroll
        for (int k = 0; k < 4; ++k)
            hTb[(size_t)(c0 + k) * B_N + tb] = bf16_1(hin[k]);
    }
}

// ============ lateral EI: Gram-MFMA weights + MFMA K@h ============
template<int S>
__global__ __launch_bounds__(256, 4) void k_lateral(
    const float* __restrict__ zbuf, const unsigned short* __restrict__ hTb,
    float* __restrict__ pAcc, float* __restrict__ pDen)
{
    __shared__ __align__(16) unsigned short zA[2][64 * 24];
    __shared__ __align__(16) unsigned short hsT[2][CH][72];
    const int tid  = threadIdx.x;
    const int lane = tid & 63;
    const int wv   = tid >> 6;
    const int l15  = lane & 15;
    const int g    = lane >> 4;
    const int rowbase = blockIdx.x * 64;
    const int t0 = (TILES * blockIdx.y) / S;
    const int t1 = (TILES * (blockIdx.y + 1)) / S;
    const int chS = tid >> 2, segS = tid & 3;

    short8v bZ;
    {
        const int irow = rowbase + 16 * wv + l15;
        const float4* zp = (const float4*)(zbuf + (size_t)irow * DL);
        uint4 Whi, Wlo; unsigned int Wc;
        z_split(zp[0], zp[1], Whi, Wlo, Wc);
        union { unsigned int u[4]; short8v v; } uh, ul, ua;
        uh.u[0]=Whi.x; uh.u[1]=Whi.y; uh.u[2]=Whi.z; uh.u[3]=Whi.w;
        ul.u[0]=Wlo.x; ul.u[1]=Wlo.y; ul.u[2]=Wlo.z; ul.u[3]=Wlo.w;
        ua.u[0] = ONE_BF16 | (ONE_BF16 << 16);
        ua.u[1] = Wc; ua.u[2] = 0; ua.u[3] = 0;
        bZ = (g == 2) ? ul.v : ((g == 3) ? ua.v : uh.v);
    }
    const int offsh = (g == 1) ? 8 : ((g == 3) ? 16 : 0);

    short8v bones;
    {
        union { unsigned int u[4]; short8v v; } uo;
        uo.u[0] = uo.u[1] = uo.u[2] = uo.u[3] = ONE_BF16 | (ONE_BF16 << 16);
        bones = uo.v;
    }

    f32x4 acc0 = {0,0,0,0}, acc1 = {0,0,0,0}, acc2 = {0,0,0,0}, acc3 = {0,0,0,0};
    f32x4 acc4 = {0,0,0,0};
    const f32x4 zc = {0,0,0,0};

    {
        const int jb = t0 * 64;
        if (tid < 64) {
            const float4* zp = (const float4*)(zbuf + (size_t)(jb + tid) * DL);
            uint4 Whi, Wlo; unsigned int Wc;
            z_split(zp[0], zp[1], Whi, Wlo, Wc);
            uint4 W2v; W2v.x = Wc; W2v.y = ONE_BF16 | (ONE_BF16 << 16);
            W2v.z = 0; W2v.w = 0;
            unsigned short* dst = &zA[0][tid * 24];
            *(uint4*)(dst)      = Whi;
            *(uint4*)(dst + 8)  = Wlo;
            *(uint4*)(dst + 16) = W2v;
        }
        const unsigned short* hs = hTb + (size_t)chS * B_N + jb + segS * 16;
        *(uint4*)(&hsT[0][chS][segS * 16])     = *(const uint4*)(hs);
        *(uint4*)(&hsT[0][chS][segS * 16 + 8]) = *(const uint4*)(hs + 8);
    }

    #pragma unroll 1
    for (int jt = t0; jt < t1; ++jt) {
        const int cur = (jt - t0) & 1;
        const bool more = (jt + 1 < t1);
        uint4 h0n, h1n;
        float4 zna, znb;
        if (more) {
            const int jb2 = (jt + 1) * 64;
            const unsigned short* hs = hTb + (size_t)chS * B_N + jb2 + segS * 16;
            h0n = *(const uint4*)(hs);
            h1n = *(const uint4*)(hs + 8);
            if (tid < 64) {
                const float4* zp = (const float4*)(zbuf + (size_t)(jb2 + tid) * DL);
                zna = zp[0]; znb = zp[1];
            }
        }
        __syncthreads();

        f32x4 gac[4];
        __builtin_amdgcn_s_setprio(1);
        #pragma unroll
        for (int t = 0; t < 4; ++t) {
            short8v az = *(const short8v*)(&zA[cur][(t * 16 + l15) * 24 + offsh]);
            gac[t] = __builtin_amdgcn_mfma_f32_16x16x32_bf16(az, bZ, zc, 0, 0, 0);
        }
        __builtin_amdgcn_s_setprio(0);

        short8v afr[2];
        #pragma unroll
        for (int kb = 0; kb < 2; ++kb) {
            float w8[8];
            #pragma unroll
            for (int m = 0; m < 8; ++m) {
                float out = gac[2 * kb + (m >> 2)][m & 3];
                float e1 = EXP2(out);
                float e2 = e1 * e1;
                float e4 = e2 * e2;
                float e8 = e4 * e4;
                w8[m] = fmaf(0.8f, e8, -e2);
            }
            union { unsigned int u[4]; short8v v; } uf;
            uf.u[0] = pack_bf16_rhu(w8[0], w8[1]);
            uf.u[1] = pack_bf16_rhu(w8[2], w8[3]);
            uf.u[2] = pack_bf16_rhu(w8[4], w8[5]);
            uf.u[3] = pack_bf16_rhu(w8[6], w8[7]);
            afr[kb] = uf.v;
        }

        __builtin_amdgcn_s_setprio(1);
        #pragma unroll
        for (int kb = 0; kb < 2; ++kb) {
            const int jo = kb * 32 + g * 8;
            short8v b0 = *(const short8v*)&hsT[cur][ 0 + l15][jo];
            short8v b1 = *(const short8v*)&hsT[cur][16 + l15][jo];
            short8v b2 = *(const short8v*)&hsT[cur][32 + l15][jo];
            short8v b3 = *(const short8v*)&hsT[cur][48 + l15][jo];
            acc0 = __builtin_amdgcn_mfma_f32_16x16x32_bf16(afr[kb], b0, acc0, 0, 0, 0);
            acc1 = __builtin_amdgcn_mfma_f32_16x16x32_bf16(afr[kb], b1, acc1, 0, 0, 0);
            acc2 = __builtin_amdgcn_mfma_f32_16x16x32_bf16(afr[kb], b2, acc2, 0, 0, 0);
            acc3 = __builtin_amdgcn_mfma_f32_16x16x32_bf16(afr[kb], b3, acc3, 0, 0, 0);
            acc4 = __builtin_amdgcn_mfma_f32_16x16x32_bf16(afr[kb], bones, acc4, 0, 0, 0);
        }
        __builtin_amdgcn_s_setprio(0);

        if (more) {
            const int nb = cur ^ 1;
            if (tid < 64) {
                uint4 Whi, Wlo; unsigned int Wc;
                z_split(zna, znb, Whi, Wlo, Wc);
                uint4 W2v; W2v.x = Wc; W2v.y = ONE_BF16 | (ONE_BF16 << 16);
                W2v.z = 0; W2v.w = 0;
                unsigned short* dst = &zA[nb][tid * 24];
                *(uint4*)(dst)      = Whi;
                *(uint4*)(dst + 8)  = Wlo;
                *(uint4*)(dst + 16) = W2v;
            }
            *(uint4*)(&hsT[nb][chS][segS * 16])     = h0n;
            *(uint4*)(&hsT[nb][chS][segS * 16 + 8]) = h1n;
        }
    }

    float* pA = pAcc + (size_t)blockIdx.y * (B_N * CH) + (size_t)rowbase * CH;
    #pragma unroll
    for (int r = 0; r < 4; ++r) {
        int gi = 16 * wv + g * 4 + r;
        pA[(size_t)gi * CH +  0 + l15] = acc0[r];
        pA[(size_t)gi * CH + 16 + l15] = acc1[r];
        pA[(size_t)gi * CH + 32 + l15] = acc2[r];
        pA[(size_t)gi * CH + 48 + l15] = acc3[r];
    }
    if (l15 == 0) {
        #pragma unroll
        for (int r = 0; r < 4; ++r)
            pDen[blockIdx.y * B_N + rowbase + 16 * wv + g * 4 + r] = acc4[r];
    }
}

// ============ final: h = hmid + GAIN*acc/den ; logits = h @ roW + rob ======
template<int S>
__global__ __launch_bounds__(256) void k_logits_h(
    const float* __restrict__ hmid, const float* __restrict__ pAcc,
    const float* __restrict__ pDen, const float* __restrict__ roW,
    const float* __restrict__ rob, float* __restrict__ out_logits,
    float* __restrict__ out_h)
{
    __shared__ float hsh[64][68];
    __shared__ float ro[CH][NCLS];
    __shared__ float rb[NCLS];
    const int tid = threadIdx.x;
    for (int l = tid; l < CH * NCLS; l += 256) ro[l / NCLS][l % NCLS] = roW[l];
    if (tid < NCLS) rb[tid] = rob[tid];
    const int rowbase = blockIdx.x * 64;
    const int r  = tid >> 2;
    const int c0 = (tid & 3) * 16;
    const int row = rowbase + r;
    float den = 1e-6f;
    #pragma unroll
    for (int s = 0; s < S; ++s) den += pDen[s * B_N + row];
    float inv = GAIN_ / den;
    #pragma unroll
    for (int q = 0; q < 4; ++q) {
        float4 a = {0.f, 0.f, 0.f, 0.f};
        #pragma unroll
        for (int s = 0; s < S; ++s) {
            float4 p = *(const float4*)(pAcc + (size_t)s * B_N * CH
                                        + (size_t)row * CH + c0 + q * 4);
            a.x += p.x; a.y += p.y; a.z += p.z; a.w += p.w;
        }
        float4 hm = *(const float4*)(hmid + (size_t)row * CH + c0 + q * 4);
        float4 hv;
        hv.x = fmaf(inv, a.x, hm.x); hv.y = fmaf(inv, a.y, hm.y);
        hv.z = fmaf(inv, a.z, hm.z); hv.w = fmaf(inv, a.w, hm.w);
        *(float4*)(&hsh[r][c0 + q * 4]) = hv;
        *(float4*)(out_h + (size_t)row * CH + c0 + q * 4) = hv;
    }
    __syncthreads();
    for (int idx = tid; idx < 64 * NCLS; idx += 256) {
        int rr = idx / NCLS, o = idx % NCLS;
        float s = rb[o];
        #pragma unroll
        for (int k = 0; k < CH; ++k) s = fmaf(hsh[rr][k], ro[k][o], s);
        out_logits[(size_t)(rowbase + rr) * NCLS + o] = s;
    }
}

// ---- per-split launch helper ----
template<int S>
static void run_all(const float* x, const float* W1, const float* b1,
                    const float* W2, const float* b2, const float* centers,
                    const float* mus, const float* projW, const float* projb,
                    const float* roW, const float* rob,
                    float* ws, float* out, hipStream_t stream)
{
    float* pAcc = ws;
    float* pDen = ws + (size_t)S * B_N * CH;
    float* zbuf = pDen + (size_t)S * B_N;
    float* hB   = zbuf + B_N * DL;
    unsigned short* hTb  = (unsigned short*)(hB + B_N * CH);   // B_N*CH bf16
    unsigned short* W1aT = hTb + (size_t)B_N * CH;             // 256*800
    unsigned short* W1bT = W1aT + (size_t)HID * KPAD;
    unsigned short* W1cT = W1bT + (size_t)HID * KPAD;
    float* H1   = ws;   // pre-loop only; fits under pAcc (S >= 4)

    float* out_logits = out;
    float* out_z      = out + 81920;
    float* out_h      = out_z + 65536;

    k_w1split<<<KPAD, HID, 0, stream>>>(W1, W1aT, W1bT, W1cT);
    k_gemm1_tanh<<<dim3(B_N / 64, HID / 64), 256, 0, stream>>>(x, W1aT, W1bT, W1cT, b1, H1);
    k_gemm2<<<B_N / 32, 256, 0, stream>>>(H1, W2, b2, zbuf);

    for (int t = 0; t < T_ITERS; ++t) {
        if (t == 0)
            k_pm_proj<S, false><<<B_N / 16, 256, 0, stream>>>(
                centers, mus, projW, projb, zbuf, hB, hTb, pAcc, pDen);
        else
            k_pm_proj<S, true><<<B_N / 16, 256, 0, stream>>>(
                centers, mus, projW, projb, zbuf, hB, hTb, pAcc, pDen);
        k_lateral<S><<<dim3(TILES, S), 256, 0, stream>>>(zbuf, hTb, pAcc, pDen);
    }

    k_logits_h<S><<<TILES, 256, 0, stream>>>(hB, pAcc, pDen, roW, rob,
                                             out_logits, out_h);
    hipMemcpyAsync(out_z, zbuf, (size_t)B_N * DL * sizeof(float),
                   hipMemcpyDeviceToDevice, stream);
}

extern "C" void kernel_launch(void* const* d_in, const int* in_sizes, int n_in,
                              void* d_out, int out_size, void* d_ws, size_t ws_size,
                              hipStream_t stream)
{
    const float* x       = (const float*)d_in[0];
    const float* W1      = (const float*)d_in[1];
    const float* b1      = (const float*)d_in[2];
    const float* W2      = (const float*)d_in[3];
    const float* b2      = (const float*)d_in[4];
    const float* centers = (const float*)d_in[5];
    const float* mus     = (const float*)d_in[6];
    const float* projW   = (const float*)d_in[7];
    const float* projb   = (const float*)d_in[8];
    const float* roW     = (const float*)d_in[9];
    const float* rob     = (const float*)d_in[10];

    float* ws  = (float*)d_ws;
    float* out = (float*)d_out;

    // floats: S*B_N*CH + S*B_N + B_N*DL + B_N*CH + B_N*CH/2 (hTb) + 3*HID*KPAD/2 (W1 split)
    const size_t extraW = (size_t)3 * HID * KPAD / 2;
    const size_t needS8 = ((size_t)8*B_N*CH + 8*B_N + B_N*DL + B_N*CH + B_N*CH/2 + extraW) * 4;
    const size_t needS4 = ((size_t)4*B_N*CH + 4*B_N + B_N*DL + B_N*CH + B_N*CH/2 + extraW) * 4;

    if (ws_size >= needS8)
        run_all<8>(x, W1, b1, W2, b2, centers, mus, projW, projb, roW, rob, ws, out, stream);
    else if (ws_size >= needS4)
        run_all<4>(x, W1, b1, W2, b2, centers, mus, projW, projb, roW, rob, ws, out, stream);
    else
        run_all<2>(x, W1, b1, W2, b2, centers, mus, projW, projb, roW, rob, ws, out, stream);
}